// Round 1
// baseline (821.496 us; speedup 1.0000x reference)
//
#include <hip/hip_runtime.h>
#include <stdint.h>

#define S_ 1024
#define E_ 1024
#define H_ 16
#define D_ 64
#define BH_ 64

typedef __attribute__((ext_vector_type(4))) float f32x4;
typedef __attribute__((ext_vector_type(8))) short bf16x8;

__device__ __forceinline__ ushort f2bf(float f) {
  union { float f; uint32_t u; } c; c.f = f;
  uint32_t u = c.u;
  return (ushort)((u + 0x7FFFu + ((u >> 16) & 1u)) >> 16);
}

// ---------------- mask bit-pack: bit = attn_mask || key_padding_mask ----------
__global__ __launch_bounds__(256) void pack_mask(const int* __restrict__ am,
                                                 const int* __restrict__ kpm,
                                                 uint32_t* __restrict__ mw) {
  size_t f = (size_t)blockIdx.x * 256 + threadIdx.x;  // [BH,S,S] flat
  int k = (int)(f & (S_ - 1));
  int bh = (int)(f >> 20);  // S*S = 2^20
  int b = bh >> 4;
  bool m = (am[f] != 0) || (kpm[b * S_ + k] != 0);
  unsigned long long bal = __ballot(m);
  if ((threadIdx.x & 63) == 0) {
    uint2 w;
    w.x = (uint32_t)bal;
    w.y = (uint32_t)(bal >> 32);
    *reinterpret_cast<uint2*>(&mw[f >> 5]) = w;  // f multiple of 64 -> aligned
  }
}

// ---------------- generic BT GEMM: C[m,n] = sum_k A[m,k]*B[n,k] ---------------
// ATYPE: 0 = A fp32, 1 = A bf16(ushort). OMODE: 0->Qh[bh][s][d], 1->Kh, 2->Vt[bh][d][s], 3->fp32 C row-major
template <int ATYPE, int OMODE>
__global__ __launch_bounds__(256) void gemm_bt(const void* __restrict__ Ap,
                                               const float* __restrict__ Bw,
                                               void* __restrict__ outp) {
  const int K = 1024, BM = 128, BN = 128, BK = 32, LDT = 48;
  __shared__ ushort As[BM * LDT];
  __shared__ ushort Bs[BN * LDT];
  const int tid = threadIdx.x, wave = tid >> 6, lane = tid & 63;
  const int l15 = lane & 15, lk = lane >> 4;
  const int wr = wave >> 1, wc = wave & 1;
  const int mb = blockIdx.x, nb = blockIdx.y;
  f32x4 acc[4][4] = {};
  for (int kt = 0; kt < K / BK; ++kt) {
    if (ATYPE == 0) {
      const float* A = (const float*)Ap;
#pragma unroll
      for (int j = 0; j < 4; ++j) {
        int c = tid + j * 256;
        int row = c >> 3, c4 = c & 7;
        float4 v = *reinterpret_cast<const float4*>(&A[(size_t)(mb * BM + row) * K + kt * BK + c4 * 4]);
        uint2 p;
        p.x = (uint32_t)f2bf(v.x) | ((uint32_t)f2bf(v.y) << 16);
        p.y = (uint32_t)f2bf(v.z) | ((uint32_t)f2bf(v.w) << 16);
        *reinterpret_cast<uint2*>(&As[row * LDT + c4 * 4]) = p;
      }
    } else {
      const ushort* A = (const ushort*)Ap;
#pragma unroll
      for (int j = 0; j < 2; ++j) {
        int c = tid + j * 256;
        int row = c >> 2, c8 = c & 3;
        uint4 v = *reinterpret_cast<const uint4*>(&A[(size_t)(mb * BM + row) * K + kt * BK + c8 * 8]);
        *reinterpret_cast<uint4*>(&As[row * LDT + c8 * 8]) = v;
      }
    }
#pragma unroll
    for (int j = 0; j < 4; ++j) {
      int c = tid + j * 256;
      int row = c >> 3, c4 = c & 7;
      float4 v = *reinterpret_cast<const float4*>(&Bw[(size_t)(nb * BN + row) * K + kt * BK + c4 * 4]);
      uint2 p;
      p.x = (uint32_t)f2bf(v.x) | ((uint32_t)f2bf(v.y) << 16);
      p.y = (uint32_t)f2bf(v.z) | ((uint32_t)f2bf(v.w) << 16);
      *reinterpret_cast<uint2*>(&Bs[row * LDT + c4 * 4]) = p;
    }
    __syncthreads();
    bf16x8 a[4], b[4];
#pragma unroll
    for (int m = 0; m < 4; ++m)
      a[m] = *reinterpret_cast<const bf16x8*>(&As[(wr * 64 + m * 16 + l15) * LDT + lk * 8]);
#pragma unroll
    for (int n = 0; n < 4; ++n)
      b[n] = *reinterpret_cast<const bf16x8*>(&Bs[(wc * 64 + n * 16 + l15) * LDT + lk * 8]);
#pragma unroll
    for (int m = 0; m < 4; ++m)
#pragma unroll
      for (int n = 0; n < 4; ++n)
        acc[m][n] = __builtin_amdgcn_mfma_f32_16x16x32_bf16(a[m], b[n], acc[m][n], 0, 0, 0);
    __syncthreads();
  }
#pragma unroll
  for (int m = 0; m < 4; ++m) {
#pragma unroll
    for (int n = 0; n < 4; ++n) {
#pragma unroll
      for (int r = 0; r < 4; ++r) {
        int gm = mb * BM + wr * 64 + m * 16 + lk * 4 + r;
        int gn = nb * BN + wc * 64 + n * 16 + l15;
        float v = acc[m][n][r];
        if (OMODE == 3) {
          ((float*)outp)[(size_t)gm * 1024 + gn] = v;
        } else {
          int bb = gm >> 10, s = gm & 1023, h = gn >> 6, d = gn & 63;
          int bh = bb * 16 + h;
          if (OMODE == 2)
            ((ushort*)outp)[((size_t)bh * D_ + d) * S_ + s] = f2bf(v);
          else
            ((ushort*)outp)[((size_t)bh * S_ + s) * D_ + d] = f2bf(v);
        }
      }
    }
  }
}

// ---------------- pass A: denom[bh,k] = sum_i (mask ? 1 : exp(QK/8)) ----------
__global__ __launch_bounds__(256) void attn_pass_a(const ushort* __restrict__ Qh,
                                                   const ushort* __restrict__ Kh,
                                                   const uint32_t* __restrict__ mw,
                                                   float* __restrict__ denom) {
  const int TI = 128, TK = 128, LD = 72;
  __shared__ ushort Qs[TI * LD];
  __shared__ ushort Ks[TK * LD];
  __shared__ float red[4][64];
  const int tid = threadIdx.x, wave = tid >> 6, lane = tid & 63;
  const int l15 = lane & 15, lk = lane >> 4;
  const int wr = wave >> 1, wc = wave & 1;
  const int bh = blockIdx.y, kb = blockIdx.x;
  const ushort* Qb = Qh + (size_t)bh * S_ * D_;
  const ushort* Kb = Kh + (size_t)bh * S_ * D_;
  const uint32_t* mrow = mw + (size_t)bh * S_ * 32;
#pragma unroll
  for (int j = 0; j < 4; ++j) {
    int c = tid + j * 256;
    int row = c >> 3, c8 = c & 7;
    *reinterpret_cast<uint4*>(&Ks[row * LD + c8 * 8]) =
        *reinterpret_cast<const uint4*>(&Kb[(size_t)(kb * TK + row) * D_ + c8 * 8]);
  }
  float csum[4] = {0.f, 0.f, 0.f, 0.f};
  for (int ib = 0; ib < S_ / TI; ++ib) {
    __syncthreads();
#pragma unroll
    for (int j = 0; j < 4; ++j) {
      int c = tid + j * 256;
      int row = c >> 3, c8 = c & 7;
      *reinterpret_cast<uint4*>(&Qs[row * LD + c8 * 8]) =
          *reinterpret_cast<const uint4*>(&Qb[(size_t)(ib * TI + row) * D_ + c8 * 8]);
    }
    __syncthreads();
    f32x4 acc[4][4] = {};
#pragma unroll
    for (int kk = 0; kk < 2; ++kk) {
      bf16x8 a[4], b[4];
#pragma unroll
      for (int m = 0; m < 4; ++m)
        a[m] = *reinterpret_cast<const bf16x8*>(&Qs[(wr * 64 + m * 16 + l15) * LD + kk * 32 + lk * 8]);
#pragma unroll
      for (int n = 0; n < 4; ++n)
        b[n] = *reinterpret_cast<const bf16x8*>(&Ks[(wc * 64 + n * 16 + l15) * LD + kk * 32 + lk * 8]);
#pragma unroll
      for (int m = 0; m < 4; ++m)
#pragma unroll
        for (int n = 0; n < 4; ++n)
          acc[m][n] = __builtin_amdgcn_mfma_f32_16x16x32_bf16(a[m], b[n], acc[m][n], 0, 0, 0);
    }
#pragma unroll
    for (int n = 0; n < 4; ++n) {
      int k = kb * TK + wc * 64 + n * 16 + l15;
      int kw = k >> 5;
      uint32_t kbit = 1u << (k & 31);
      float part = 0.f;
#pragma unroll
      for (int m = 0; m < 4; ++m) {
        int i0 = ib * TI + wr * 64 + m * 16 + lk * 4;
#pragma unroll
        for (int r = 0; r < 4; ++r) {
          bool msk = (mrow[(size_t)(i0 + r) * 32 + kw] & kbit) != 0;
          float s = acc[m][n][r] * 0.125f;
          part += msk ? 1.0f : __expf(s);
        }
      }
      csum[n] += part;
    }
  }
#pragma unroll
  for (int n = 0; n < 4; ++n) {
    float v = csum[n];
    v += __shfl_xor(v, 16);
    v += __shfl_xor(v, 32);
    csum[n] = v;
  }
  __syncthreads();
  if (lane < 16) {
#pragma unroll
    for (int n = 0; n < 4; ++n) red[wave][n * 16 + l15] = csum[n];
  }
  __syncthreads();
  if (tid < 128) {
    int wcx = tid >> 6, col = tid & 63;
    denom[(size_t)bh * S_ + kb * TK + wcx * 64 + col] = red[wcx][col] + red[wcx + 2][col];
  }
}

// ---------------- pass B: attn = (mask?0:exp(QK/8)/denom) @ V -----------------
__global__ __launch_bounds__(256) void attn_pass_b(const ushort* __restrict__ Qh,
                                                   const ushort* __restrict__ Kh,
                                                   const ushort* __restrict__ Vt,
                                                   const uint32_t* __restrict__ mw,
                                                   const float* __restrict__ denom,
                                                   ushort* __restrict__ An) {
  const int TI = 128, TK = 64, LD = 72;
  __shared__ ushort Qs[TI * LD];
  __shared__ ushort Ks[TK * LD];
  __shared__ ushort Ws[TI * LD];
  __shared__ float dinv[TK];
  const int tid = threadIdx.x, wave = tid >> 6, lane = tid & 63;
  const int l15 = lane & 15, lk = lane >> 4;
  const int wr = wave >> 1, wc = wave & 1;
  const int bh = blockIdx.y, ib = blockIdx.x;
  const ushort* Qb = Qh + (size_t)bh * S_ * D_;
  const ushort* Kb = Kh + (size_t)bh * S_ * D_;
  const ushort* Vb = Vt + (size_t)bh * D_ * S_;
  const uint32_t* mrow = mw + (size_t)bh * S_ * 32;
#pragma unroll
  for (int j = 0; j < 4; ++j) {
    int c = tid + j * 256;
    int row = c >> 3, c8 = c & 7;
    *reinterpret_cast<uint4*>(&Qs[row * LD + c8 * 8]) =
        *reinterpret_cast<const uint4*>(&Qb[(size_t)(ib * TI + row) * D_ + c8 * 8]);
  }
  f32x4 acc2[2][4] = {};
  for (int kt = 0; kt < S_ / TK; ++kt) {
    __syncthreads();
#pragma unroll
    for (int j = 0; j < 2; ++j) {
      int c = tid + j * 256;
      int row = c >> 3, c8 = c & 7;
      *reinterpret_cast<uint4*>(&Ks[row * LD + c8 * 8]) =
          *reinterpret_cast<const uint4*>(&Kb[(size_t)(kt * TK + row) * D_ + c8 * 8]);
    }
    if (tid < TK) dinv[tid] = 1.0f / denom[(size_t)bh * S_ + kt * TK + tid];
    __syncthreads();
    f32x4 acc[4][2] = {};
#pragma unroll
    for (int kk = 0; kk < 2; ++kk) {
      bf16x8 a[4], b[2];
#pragma unroll
      for (int m = 0; m < 4; ++m)
        a[m] = *reinterpret_cast<const bf16x8*>(&Qs[(wr * 64 + m * 16 + l15) * LD + kk * 32 + lk * 8]);
#pragma unroll
      for (int n = 0; n < 2; ++n)
        b[n] = *reinterpret_cast<const bf16x8*>(&Ks[(wc * 32 + n * 16 + l15) * LD + kk * 32 + lk * 8]);
#pragma unroll
      for (int m = 0; m < 4; ++m)
#pragma unroll
        for (int n = 0; n < 2; ++n)
          acc[m][n] = __builtin_amdgcn_mfma_f32_16x16x32_bf16(a[m], b[n], acc[m][n], 0, 0, 0);
    }
#pragma unroll
    for (int n = 0; n < 2; ++n) {
      int kcol = wc * 32 + n * 16 + l15;
      int kg = kt * TK + kcol;
      int kw = kg >> 5;
      uint32_t kbit = 1u << (kg & 31);
      float di = dinv[kcol];
#pragma unroll
      for (int m = 0; m < 4; ++m) {
        int lrow = wr * 64 + m * 16 + lk * 4;
        int i0 = ib * TI + lrow;
#pragma unroll
        for (int r = 0; r < 4; ++r) {
          bool msk = (mrow[(size_t)(i0 + r) * 32 + kw] & kbit) != 0;
          float s = acc[m][n][r] * 0.125f;
          float wv = msk ? 0.f : __expf(s) * di;
          Ws[(lrow + r) * LD + kcol] = f2bf(wv);
        }
      }
    }
    __syncthreads();
#pragma unroll
    for (int kk = 0; kk < 2; ++kk) {
      bf16x8 a2[2], b2[4];
#pragma unroll
      for (int m = 0; m < 2; ++m)
        a2[m] = *reinterpret_cast<const bf16x8*>(&Ws[(wave * 32 + m * 16 + l15) * LD + kk * 32 + lk * 8]);
#pragma unroll
      for (int n = 0; n < 4; ++n)
        b2[n] = *reinterpret_cast<const bf16x8*>(&Vb[(size_t)(n * 16 + l15) * S_ + kt * TK + kk * 32 + lk * 8]);
#pragma unroll
      for (int m = 0; m < 2; ++m)
#pragma unroll
        for (int n = 0; n < 4; ++n)
          acc2[m][n] = __builtin_amdgcn_mfma_f32_16x16x32_bf16(a2[m], b2[n], acc2[m][n], 0, 0, 0);
    }
  }
  const int b_ = bh >> 4, h = bh & 15;
#pragma unroll
  for (int m = 0; m < 2; ++m) {
#pragma unroll
    for (int n = 0; n < 4; ++n) {
#pragma unroll
      for (int r = 0; r < 4; ++r) {
        int i = ib * TI + wave * 32 + m * 16 + lk * 4 + r;
        int d = n * 16 + l15;
        An[((size_t)(b_ * S_ + i)) * E_ + h * D_ + d] = f2bf(acc2[m][n][r]);
      }
    }
  }
}

extern "C" void kernel_launch(void* const* d_in, const int* in_sizes, int n_in,
                              void* d_out, int out_size, void* d_ws, size_t ws_size,
                              hipStream_t stream) {
  const float* q = (const float*)d_in[0];
  const float* k = (const float*)d_in[1];
  const float* v = (const float*)d_in[2];
  const int* am = (const int*)d_in[3];
  const int* kpm = (const int*)d_in[4];
  const float* Wq = (const float*)d_in[5];
  const float* Wk = (const float*)d_in[6];
  const float* Wv = (const float*)d_in[7];
  const float* Wo = (const float*)d_in[8];
  float* out = (float*)d_out;

  uint8_t* ws = (uint8_t*)d_ws;
  ushort* Qh = (ushort*)(ws + (0ull << 20));    // [BH,S,D] bf16, 8 MiB
  ushort* Kh = (ushort*)(ws + (8ull << 20));    // [BH,S,D] bf16, 8 MiB
  ushort* Vt = (ushort*)(ws + (16ull << 20));   // [BH,D,S] bf16, 8 MiB
  ushort* An = (ushort*)(ws + (24ull << 20));   // [B*S,E]  bf16, 8 MiB
  uint32_t* MW = (uint32_t*)(ws + (32ull << 20));  // packed mask bits, 8 MiB
  float* Dn = (float*)(ws + (40ull << 20));     // denom [BH,S], 256 KiB

  pack_mask<<<dim3((BH_ * S_ * S_) / 256), 256, 0, stream>>>(am, kpm, MW);
  gemm_bt<0, 0><<<dim3(32, 8), 256, 0, stream>>>(q, Wq, Qh);
  gemm_bt<0, 1><<<dim3(32, 8), 256, 0, stream>>>(k, Wk, Kh);
  gemm_bt<0, 2><<<dim3(32, 8), 256, 0, stream>>>(v, Wv, Vt);
  attn_pass_a<<<dim3(8, 64), 256, 0, stream>>>(Qh, Kh, MW, Dn);
  attn_pass_b<<<dim3(8, 64), 256, 0, stream>>>(Qh, Kh, Vt, MW, Dn, An);
  gemm_bt<1, 3><<<dim3(32, 8), 256, 0, stream>>>(An, Wo, out);
}

// Round 2
// 581.276 us; speedup vs baseline: 1.4133x; 1.4133x over previous
//
#include <hip/hip_runtime.h>
#include <stdint.h>

#define S_ 1024
#define E_ 1024
#define H_ 16
#define D_ 64
#define BH_ 64

typedef __attribute__((ext_vector_type(4))) float f32x4;
typedef __attribute__((ext_vector_type(8))) short bf16x8;

__device__ __forceinline__ ushort f2bf(float f) {
  union { float f; uint32_t u; } c; c.f = f;
  uint32_t u = c.u;
  return (ushort)((u + 0x7FFFu + ((u >> 16) & 1u)) >> 16);
}

__device__ __forceinline__ void gl_lds16(const void* g, void* l) {
  __builtin_amdgcn_global_load_lds((__attribute__((address_space(1))) void*)(g),
                                   (__attribute__((address_space(3))) void*)(l), 16, 0, 0);
}

// ---------------- fp32 -> bf16 convert: q,k,v,Wq,Wk,Wv,Wo into one region -----
__global__ __launch_bounds__(256) void cvt_bf16(const float* __restrict__ q,
                                                const float* __restrict__ k,
                                                const float* __restrict__ v,
                                                const float* __restrict__ wq,
                                                const float* __restrict__ wk,
                                                const float* __restrict__ wv,
                                                const float* __restrict__ wo,
                                                ushort* __restrict__ dst) {
  size_t i = ((size_t)blockIdx.x * 256 + threadIdx.x) * 4;
  const size_t M4 = 4u << 20, M1 = 1u << 20;
  const float* src;
  size_t off;
  if (i < M4) { src = q; off = i; }
  else if (i < 2 * M4) { src = k; off = i - M4; }
  else if (i < 3 * M4) { src = v; off = i - 2 * M4; }
  else if (i < 3 * M4 + M1) { src = wq; off = i - 3 * M4; }
  else if (i < 3 * M4 + 2 * M1) { src = wk; off = i - (3 * M4 + M1); }
  else if (i < 3 * M4 + 3 * M1) { src = wv; off = i - (3 * M4 + 2 * M1); }
  else { src = wo; off = i - (3 * M4 + 3 * M1); }
  float4 f = *reinterpret_cast<const float4*>(src + off);
  ushort4 o;
  o.x = f2bf(f.x); o.y = f2bf(f.y); o.z = f2bf(f.z); o.w = f2bf(f.w);
  *reinterpret_cast<ushort4*>(dst + i) = o;
}

// ---------------- mask bit-pack: bit = attn_mask || key_padding_mask ----------
__global__ __launch_bounds__(256) void pack_mask(const int* __restrict__ am,
                                                 const int* __restrict__ kpm,
                                                 uint32_t* __restrict__ mw) {
  size_t t = (size_t)blockIdx.x * 256 + threadIdx.x;  // handles elems [4t,4t+4)
  size_t f = t * 4;
  int k = (int)(f & (S_ - 1));
  int b = (int)(f >> 24);  // f>>20 = bh, bh>>4 = b
  int4 a = *reinterpret_cast<const int4*>(am + f);
  int4 kp = *reinterpret_cast<const int4*>(kpm + (size_t)b * S_ + k);
  uint32_t nib = (uint32_t)((a.x | kp.x) != 0) | ((uint32_t)((a.y | kp.y) != 0) << 1) |
                 ((uint32_t)((a.z | kp.z) != 0) << 2) | ((uint32_t)((a.w | kp.w) != 0) << 3);
  uint32_t v = nib << ((threadIdx.x & 7) * 4);
  v |= __shfl_xor(v, 1);
  v |= __shfl_xor(v, 2);
  v |= __shfl_xor(v, 4);
  if ((threadIdx.x & 7) == 0) mw[t >> 3] = v;
}

// ---------------- fused projection GEMM: z=0 Q, z=1 K, z=2 V(transposed) -----
// C[m,n] = sum_k A[m,k]*B[n,k], all bf16, 128x128 tile, global_load_lds staging.
__global__ __launch_bounds__(256) void gemm_proj(const ushort* __restrict__ qkv,
                                                 const ushort* __restrict__ wts,
                                                 ushort* __restrict__ QKo,
                                                 ushort* __restrict__ Vt) {
  const int K = 1024, BM = 128, BK = 32;
  __shared__ ushort As[BM * BK];
  __shared__ ushort Bs[BM * BK];
  const int tid = threadIdx.x, wave = tid >> 6, lane = tid & 63;
  const int l15 = lane & 15, lk = lane >> 4;
  const int wr = wave >> 1, wc = wave & 1;
  const int mb = blockIdx.x, nb = blockIdx.y, z = blockIdx.z;
  const ushort* A = qkv + (size_t)z * (4u << 20);
  const ushort* Bw = wts + (size_t)z * (1u << 20);
  const int srow = (lane >> 2);          // row within 16-row chunk
  const int scol = (lane & 3) * 8;       // ushort col within 32
  f32x4 acc[4][4] = {};
  for (int kt = 0; kt < K / BK; ++kt) {
#pragma unroll
    for (int c = 0; c < 2; ++c) {
      int ch = wave * 2 + c;
      int row = ch * 16 + srow;
      gl_lds16(&A[(size_t)(mb * BM + row) * K + kt * BK + scol], &As[ch * 512]);
      gl_lds16(&Bw[(size_t)(nb * BM + row) * K + kt * BK + scol], &Bs[ch * 512]);
    }
    __syncthreads();
    bf16x8 a[4], b[4];
#pragma unroll
    for (int m = 0; m < 4; ++m)
      a[m] = *reinterpret_cast<const bf16x8*>(&As[(wr * 64 + m * 16 + l15) * BK + lk * 8]);
#pragma unroll
    for (int n = 0; n < 4; ++n)
      b[n] = *reinterpret_cast<const bf16x8*>(&Bs[(wc * 64 + n * 16 + l15) * BK + lk * 8]);
#pragma unroll
    for (int m = 0; m < 4; ++m)
#pragma unroll
      for (int n = 0; n < 4; ++n)
        acc[m][n] = __builtin_amdgcn_mfma_f32_16x16x32_bf16(a[m], b[n], acc[m][n], 0, 0, 0);
    __syncthreads();
  }
#pragma unroll
  for (int m = 0; m < 4; ++m) {
#pragma unroll
    for (int n = 0; n < 4; ++n) {
#pragma unroll
      for (int r = 0; r < 4; ++r) {
        int gm = mb * BM + wr * 64 + m * 16 + lk * 4 + r;
        int gn = nb * BM + wc * 64 + n * 16 + l15;
        int bb = gm >> 10, s = gm & 1023, h = gn >> 6, d = gn & 63;
        int bh = bb * 16 + h;
        ushort v = f2bf(acc[m][n][r]);
        if (z == 2)
          Vt[((size_t)bh * D_ + d) * S_ + s] = v;
        else
          QKo[(size_t)z * (4u << 20) + ((size_t)bh * S_ + s) * D_ + d] = v;
      }
    }
  }
}

// ---------------- output GEMM: out[m,n] = sum_k An[m,k]*Wo[n,k], fp32 out -----
__global__ __launch_bounds__(256) void gemm_out(const ushort* __restrict__ An,
                                                const ushort* __restrict__ Bw,
                                                float* __restrict__ outp) {
  const int K = 1024, BM = 128, BN = 64, BK = 32;
  __shared__ ushort As[BM * BK];
  __shared__ ushort Bs[BN * BK];
  const int tid = threadIdx.x, wave = tid >> 6, lane = tid & 63;
  const int l15 = lane & 15, lk = lane >> 4;
  const int wr = wave >> 1, wc = wave & 1;
  const int mb = blockIdx.x, nb = blockIdx.y;
  const int srow = (lane >> 2), scol = (lane & 3) * 8;
  f32x4 acc[4][2] = {};
  for (int kt = 0; kt < K / BK; ++kt) {
#pragma unroll
    for (int c = 0; c < 2; ++c) {
      int ch = wave * 2 + c;
      int row = ch * 16 + srow;
      gl_lds16(&An[(size_t)(mb * BM + row) * K + kt * BK + scol], &As[ch * 512]);
    }
    {
      int row = wave * 16 + srow;
      gl_lds16(&Bw[(size_t)(nb * BN + row) * K + kt * BK + scol], &Bs[wave * 512]);
    }
    __syncthreads();
    bf16x8 a[4], b[2];
#pragma unroll
    for (int m = 0; m < 4; ++m)
      a[m] = *reinterpret_cast<const bf16x8*>(&As[(wr * 64 + m * 16 + l15) * BK + lk * 8]);
#pragma unroll
    for (int n = 0; n < 2; ++n)
      b[n] = *reinterpret_cast<const bf16x8*>(&Bs[(wc * 32 + n * 16 + l15) * BK + lk * 8]);
#pragma unroll
    for (int m = 0; m < 4; ++m)
#pragma unroll
      for (int n = 0; n < 2; ++n)
        acc[m][n] = __builtin_amdgcn_mfma_f32_16x16x32_bf16(a[m], b[n], acc[m][n], 0, 0, 0);
    __syncthreads();
  }
#pragma unroll
  for (int m = 0; m < 4; ++m) {
#pragma unroll
    for (int n = 0; n < 2; ++n) {
#pragma unroll
      for (int r = 0; r < 4; ++r) {
        int gm = mb * BM + wr * 64 + m * 16 + lk * 4 + r;
        int gn = nb * BN + wc * 32 + n * 16 + l15;
        outp[(size_t)gm * 1024 + gn] = acc[m][n][r];
      }
    }
  }
}

// ---------------- pass A: denom[bh,k] = sum_i (mask ? 1 : exp(QK/8)) ----------
__global__ __launch_bounds__(256) void attn_pass_a(const ushort* __restrict__ Qh,
                                                   const ushort* __restrict__ Kh,
                                                   const uint32_t* __restrict__ mw,
                                                   float* __restrict__ denom) {
  const int TI = 128, TK = 128, LD = 72;
  __shared__ ushort Qs[TI * LD];
  __shared__ ushort Ks[TK * LD];
  __shared__ uint32_t Ms[TI * 4];
  __shared__ float red[4][64];
  const int tid = threadIdx.x, wave = tid >> 6, lane = tid & 63;
  const int l15 = lane & 15, lk = lane >> 4;
  const int wr = wave >> 1, wc = wave & 1;
  const int bh = blockIdx.y, kb = blockIdx.x;
  const ushort* Qb = Qh + (size_t)bh * S_ * D_;
  const ushort* Kb = Kh + (size_t)bh * S_ * D_;
  const uint32_t* mrow = mw + (size_t)bh * S_ * 32;
#pragma unroll
  for (int j = 0; j < 4; ++j) {
    int c = tid + j * 256;
    int row = c >> 3, c8 = c & 7;
    *reinterpret_cast<uint4*>(&Ks[row * LD + c8 * 8]) =
        *reinterpret_cast<const uint4*>(&Kb[(size_t)(kb * TK + row) * D_ + c8 * 8]);
  }
  float csum[4] = {0.f, 0.f, 0.f, 0.f};
  for (int ib = 0; ib < S_ / TI; ++ib) {
    __syncthreads();
#pragma unroll
    for (int j = 0; j < 4; ++j) {
      int c = tid + j * 256;
      int row = c >> 3, c8 = c & 7;
      *reinterpret_cast<uint4*>(&Qs[row * LD + c8 * 8]) =
          *reinterpret_cast<const uint4*>(&Qb[(size_t)(ib * TI + row) * D_ + c8 * 8]);
    }
    if (tid < 512) Ms[tid] = mrow[(size_t)(ib * TI + (tid >> 2)) * 32 + kb * 4 + (tid & 3)];
    __syncthreads();
    f32x4 acc[4][4] = {};
#pragma unroll
    for (int kk = 0; kk < 2; ++kk) {
      bf16x8 a[4], b[4];
#pragma unroll
      for (int m = 0; m < 4; ++m)
        a[m] = *reinterpret_cast<const bf16x8*>(&Qs[(wr * 64 + m * 16 + l15) * LD + kk * 32 + lk * 8]);
#pragma unroll
      for (int n = 0; n < 4; ++n)
        b[n] = *reinterpret_cast<const bf16x8*>(&Ks[(wc * 64 + n * 16 + l15) * LD + kk * 32 + lk * 8]);
#pragma unroll
      for (int m = 0; m < 4; ++m)
#pragma unroll
        for (int n = 0; n < 4; ++n)
          acc[m][n] = __builtin_amdgcn_mfma_f32_16x16x32_bf16(a[m], b[n], acc[m][n], 0, 0, 0);
    }
#pragma unroll
    for (int n = 0; n < 4; ++n) {
      int kwl = wc * 2 + (n >> 1);
      int kbit = (n & 1) * 16 + l15;
      float part = 0.f;
#pragma unroll
      for (int m = 0; m < 4; ++m) {
        int lr0 = wr * 64 + m * 16 + lk * 4;
#pragma unroll
        for (int r = 0; r < 4; ++r) {
          bool msk = (Ms[(lr0 + r) * 4 + kwl] >> kbit) & 1;
          float s = acc[m][n][r] * 0.125f;
          part += msk ? 1.0f : __expf(s);
        }
      }
      csum[n] += part;
    }
  }
#pragma unroll
  for (int n = 0; n < 4; ++n) {
    float v = csum[n];
    v += __shfl_xor(v, 16);
    v += __shfl_xor(v, 32);
    csum[n] = v;
  }
  __syncthreads();
  if (lane < 16) {
#pragma unroll
    for (int n = 0; n < 4; ++n) red[wave][n * 16 + l15] = csum[n];
  }
  __syncthreads();
  if (tid < 128) {
    int wcx = tid >> 6, col = tid & 63;
    denom[(size_t)bh * S_ + kb * TK + wcx * 64 + col] = red[wcx][col] + red[wcx + 2][col];
  }
}

// ---------------- pass B: attn = (mask?0:exp(QK/8)/denom) @ V -----------------
__global__ __launch_bounds__(256) void attn_pass_b(const ushort* __restrict__ Qh,
                                                   const ushort* __restrict__ Kh,
                                                   const ushort* __restrict__ Vt,
                                                   const uint32_t* __restrict__ mw,
                                                   const float* __restrict__ denom,
                                                   ushort* __restrict__ An) {
  const int TI = 128, TK = 64, LD = 72;
  __shared__ ushort Qs[TI * LD];
  __shared__ ushort Ks[TK * LD];
  __shared__ ushort Ws[TI * LD];
  __shared__ uint32_t Ms[TI * 2];
  __shared__ float dinv[TK];
  const int tid = threadIdx.x, wave = tid >> 6, lane = tid & 63;
  const int l15 = lane & 15, lk = lane >> 4;
  const int wr = wave >> 1, wc = wave & 1;
  const int bh = blockIdx.y, ib = blockIdx.x;
  const ushort* Qb = Qh + (size_t)bh * S_ * D_;
  const ushort* Kb = Kh + (size_t)bh * S_ * D_;
  const ushort* Vb = Vt + (size_t)bh * D_ * S_;
  const uint32_t* mrow = mw + (size_t)bh * S_ * 32;
#pragma unroll
  for (int j = 0; j < 4; ++j) {
    int c = tid + j * 256;
    int row = c >> 3, c8 = c & 7;
    *reinterpret_cast<uint4*>(&Qs[row * LD + c8 * 8]) =
        *reinterpret_cast<const uint4*>(&Qb[(size_t)(ib * TI + row) * D_ + c8 * 8]);
  }
  f32x4 acc2[2][4] = {};
  for (int kt = 0; kt < S_ / TK; ++kt) {
    __syncthreads();
#pragma unroll
    for (int j = 0; j < 2; ++j) {
      int c = tid + j * 256;
      int row = c >> 3, c8 = c & 7;
      *reinterpret_cast<uint4*>(&Ks[row * LD + c8 * 8]) =
          *reinterpret_cast<const uint4*>(&Kb[(size_t)(kt * TK + row) * D_ + c8 * 8]);
    }
    if (tid < 256) Ms[tid] = mrow[(size_t)(ib * TI + (tid >> 1)) * 32 + kt * 2 + (tid & 1)];
    if (tid < TK) dinv[tid] = 1.0f / denom[(size_t)bh * S_ + kt * TK + tid];
    __syncthreads();
    f32x4 acc[4][2] = {};
#pragma unroll
    for (int kk = 0; kk < 2; ++kk) {
      bf16x8 a[4], b[2];
#pragma unroll
      for (int m = 0; m < 4; ++m)
        a[m] = *reinterpret_cast<const bf16x8*>(&Qs[(wr * 64 + m * 16 + l15) * LD + kk * 32 + lk * 8]);
#pragma unroll
      for (int n = 0; n < 2; ++n)
        b[n] = *reinterpret_cast<const bf16x8*>(&Ks[(wc * 32 + n * 16 + l15) * LD + kk * 32 + lk * 8]);
#pragma unroll
      for (int m = 0; m < 4; ++m)
#pragma unroll
        for (int n = 0; n < 2; ++n)
          acc[m][n] = __builtin_amdgcn_mfma_f32_16x16x32_bf16(a[m], b[n], acc[m][n], 0, 0, 0);
    }
#pragma unroll
    for (int n = 0; n < 2; ++n) {
      int kcol = wc * 32 + n * 16 + l15;
      int kwl = kcol >> 5;
      int kbit = kcol & 31;
      float di = dinv[kcol];
#pragma unroll
      for (int m = 0; m < 4; ++m) {
        int lrow = wr * 64 + m * 16 + lk * 4;
#pragma unroll
        for (int r = 0; r < 4; ++r) {
          bool msk = (Ms[(lrow + r) * 2 + kwl] >> kbit) & 1;
          float s = acc[m][n][r] * 0.125f;
          float wv = msk ? 0.f : __expf(s) * di;
          Ws[(lrow + r) * LD + kcol] = f2bf(wv);
        }
      }
    }
    __syncthreads();
#pragma unroll
    for (int kk = 0; kk < 2; ++kk) {
      bf16x8 a2[2], b2[4];
#pragma unroll
      for (int m = 0; m < 2; ++m)
        a2[m] = *reinterpret_cast<const bf16x8*>(&Ws[(wave * 32 + m * 16 + l15) * LD + kk * 32 + lk * 8]);
#pragma unroll
      for (int n = 0; n < 4; ++n)
        b2[n] = *reinterpret_cast<const bf16x8*>(&Vb[(size_t)(n * 16 + l15) * S_ + kt * TK + kk * 32 + lk * 8]);
#pragma unroll
      for (int m = 0; m < 2; ++m)
#pragma unroll
        for (int n = 0; n < 4; ++n)
          acc2[m][n] = __builtin_amdgcn_mfma_f32_16x16x32_bf16(a2[m], b2[n], acc2[m][n], 0, 0, 0);
    }
  }
  const int b_ = bh >> 4, h = bh & 15;
#pragma unroll
  for (int m = 0; m < 2; ++m) {
#pragma unroll
    for (int n = 0; n < 4; ++n) {
#pragma unroll
      for (int r = 0; r < 4; ++r) {
        int i = ib * TI + wave * 32 + m * 16 + lk * 4 + r;
        int d = n * 16 + l15;
        An[((size_t)(b_ * S_ + i)) * E_ + h * D_ + d] = f2bf(acc2[m][n][r]);
      }
    }
  }
}

extern "C" void kernel_launch(void* const* d_in, const int* in_sizes, int n_in,
                              void* d_out, int out_size, void* d_ws, size_t ws_size,
                              hipStream_t stream) {
  const float* q = (const float*)d_in[0];
  const float* k = (const float*)d_in[1];
  const float* v = (const float*)d_in[2];
  const int* am = (const int*)d_in[3];
  const int* kpm = (const int*)d_in[4];
  const float* Wq = (const float*)d_in[5];
  const float* Wk = (const float*)d_in[6];
  const float* Wv = (const float*)d_in[7];
  const float* Wo = (const float*)d_in[8];
  float* out = (float*)d_out;

  ushort* cvt = (ushort*)d_ws;            // 16M bf16 elems = 32 MiB
  ushort* qkv = cvt;                      // q,k,v @ 0,4M,8M elems
  ushort* wts = cvt + (12u << 20);        // Wq,Wk,Wv @ 12,13,14M elems
  ushort* wob = cvt + (15u << 20);        // Wo @ 15M elems
  uint8_t* ws = (uint8_t*)d_ws;
  ushort* Qh = (ushort*)(ws + (32ull << 20));  // [BH,S,D] 8 MiB
  ushort* Kh = (ushort*)(ws + (40ull << 20));  // [BH,S,D] 8 MiB
  ushort* Vt = (ushort*)(ws + (48ull << 20));  // [BH,D,S] 8 MiB
  ushort* An = qkv;                            // reuse q region (dead after proj)
  uint32_t* MW = (uint32_t*)(ws + (56ull << 20));  // packed mask 8 MiB
  float* Dn = (float*)(ws + (64ull << 20));        // denom [BH,S] 256 KiB

  cvt_bf16<<<16384, 256, 0, stream>>>(q, k, v, Wq, Wk, Wv, Wo, cvt);
  pack_mask<<<65536, 256, 0, stream>>>(am, kpm, MW);
  gemm_proj<<<dim3(32, 8, 3), 256, 0, stream>>>(qkv, wts, Qh, Vt);
  attn_pass_a<<<dim3(8, 64), 256, 0, stream>>>(Qh, Kh, MW, Dn);
  attn_pass_b<<<dim3(8, 64), 256, 0, stream>>>(Qh, Kh, Vt, MW, Dn, An);
  gemm_out<<<dim3(32, 16), 256, 0, stream>>>(An, wob, out);
}

// Round 4
// 567.124 us; speedup vs baseline: 1.4485x; 1.0250x over previous
//
#include <hip/hip_runtime.h>
#include <stdint.h>

#define S_ 1024
#define E_ 1024
#define H_ 16
#define D_ 64
#define BH_ 64

typedef __attribute__((ext_vector_type(4))) float f32x4;
typedef __attribute__((ext_vector_type(8))) _Float16 f16x8;

__device__ __forceinline__ void gl_lds16(const void* g, void* l) {
  __builtin_amdgcn_global_load_lds((__attribute__((address_space(1))) void*)(g),
                                   (__attribute__((address_space(3))) void*)(l), 16, 0, 0);
}

// ---------------- fp32 -> fp16 convert: q,k,v,Wq,Wk,Wv,Wo into one region -----
__global__ __launch_bounds__(256) void cvt_f16(const float* __restrict__ q,
                                               const float* __restrict__ k,
                                               const float* __restrict__ v,
                                               const float* __restrict__ wq,
                                               const float* __restrict__ wk,
                                               const float* __restrict__ wv,
                                               const float* __restrict__ wo,
                                               _Float16* __restrict__ dst) {
  size_t i = ((size_t)blockIdx.x * 256 + threadIdx.x) * 4;
  const size_t M4 = 4u << 20, M1 = 1u << 20;
  const float* src;
  size_t off;
  if (i < M4) { src = q; off = i; }
  else if (i < 2 * M4) { src = k; off = i - M4; }
  else if (i < 3 * M4) { src = v; off = i - 2 * M4; }
  else if (i < 3 * M4 + M1) { src = wq; off = i - 3 * M4; }
  else if (i < 3 * M4 + 2 * M1) { src = wk; off = i - (3 * M4 + M1); }
  else if (i < 3 * M4 + 3 * M1) { src = wv; off = i - (3 * M4 + 2 * M1); }
  else { src = wo; off = i - (3 * M4 + 3 * M1); }
  float4 f = *reinterpret_cast<const float4*>(src + off);
  _Float16 h[4];
  h[0] = (_Float16)f.x; h[1] = (_Float16)f.y; h[2] = (_Float16)f.z; h[3] = (_Float16)f.w;
  *reinterpret_cast<uint2*>(dst + i) = *reinterpret_cast<uint2*>(h);
}

// ---------------- mask bit-pack: bit = attn_mask || key_padding_mask ----------
__global__ __launch_bounds__(256) void pack_mask(const int* __restrict__ am,
                                                 const int* __restrict__ kpm,
                                                 uint32_t* __restrict__ mw) {
  size_t t = (size_t)blockIdx.x * 256 + threadIdx.x;  // handles elems [4t,4t+4)
  size_t f = t * 4;
  int k = (int)(f & (S_ - 1));
  int b = (int)(f >> 24);
  int4 a = *reinterpret_cast<const int4*>(am + f);
  int4 kp = *reinterpret_cast<const int4*>(kpm + (size_t)b * S_ + k);
  uint32_t nib = (uint32_t)((a.x | kp.x) != 0) | ((uint32_t)((a.y | kp.y) != 0) << 1) |
                 ((uint32_t)((a.z | kp.z) != 0) << 2) | ((uint32_t)((a.w | kp.w) != 0) << 3);
  uint32_t v = nib << ((threadIdx.x & 7) * 4);
  v |= __shfl_xor(v, 1);
  v |= __shfl_xor(v, 2);
  v |= __shfl_xor(v, 4);
  if ((threadIdx.x & 7) == 0) mw[t >> 3] = v;
}

// ---------------- fused projection GEMM: z=0 Q(/8), z=1 K, z=2 V(transposed) --
__global__ __launch_bounds__(256) void gemm_proj(const _Float16* __restrict__ qkv,
                                                 const _Float16* __restrict__ wts,
                                                 _Float16* __restrict__ QKo,
                                                 _Float16* __restrict__ Vt) {
  const int K = 1024, BM = 128, BK = 32;
  __shared__ __align__(16) _Float16 As[BM * BK];
  __shared__ __align__(16) _Float16 Bs[BM * BK];
  const int tid = threadIdx.x, wave = tid >> 6, lane = tid & 63;
  const int l15 = lane & 15, lk = lane >> 4;
  const int wr = wave >> 1, wc = wave & 1;
  const int mb = blockIdx.x, nb = blockIdx.y, z = blockIdx.z;
  const _Float16* A = qkv + (size_t)z * (4u << 20);
  const _Float16* Bw = wts + (size_t)z * (1u << 20);
  const int srow = (lane >> 2);
  const int scol = (lane & 3) * 8;
  f32x4 acc[4][4] = {};
  for (int kt = 0; kt < K / BK; ++kt) {
#pragma unroll
    for (int c = 0; c < 2; ++c) {
      int ch = wave * 2 + c;
      int row = ch * 16 + srow;
      gl_lds16(&A[(size_t)(mb * BM + row) * K + kt * BK + scol], &As[ch * 512]);
      gl_lds16(&Bw[(size_t)(nb * BM + row) * K + kt * BK + scol], &Bs[ch * 512]);
    }
    __syncthreads();
    f16x8 a[4], b[4];
#pragma unroll
    for (int m = 0; m < 4; ++m)
      a[m] = *reinterpret_cast<const f16x8*>(&As[(wr * 64 + m * 16 + l15) * BK + lk * 8]);
#pragma unroll
    for (int n = 0; n < 4; ++n)
      b[n] = *reinterpret_cast<const f16x8*>(&Bs[(wc * 64 + n * 16 + l15) * BK + lk * 8]);
#pragma unroll
    for (int m = 0; m < 4; ++m)
#pragma unroll
      for (int n = 0; n < 4; ++n)
        acc[m][n] = __builtin_amdgcn_mfma_f32_16x16x32_f16(a[m], b[n], acc[m][n], 0, 0, 0);
    __syncthreads();
  }
  const float qs = (z == 0) ? 0.125f : 1.0f;
#pragma unroll
  for (int m = 0; m < 4; ++m) {
#pragma unroll
    for (int n = 0; n < 4; ++n) {
#pragma unroll
      for (int r = 0; r < 4; ++r) {
        int gm = mb * BM + wr * 64 + m * 16 + lk * 4 + r;
        int gn = nb * BM + wc * 64 + n * 16 + l15;
        int bb = gm >> 10, s = gm & 1023, h = gn >> 6, d = gn & 63;
        int bh = bb * 16 + h;
        _Float16 v = (_Float16)(acc[m][n][r] * qs);
        if (z == 2)
          Vt[((size_t)bh * D_ + d) * S_ + s] = v;
        else
          QKo[(size_t)z * (4u << 20) + ((size_t)bh * S_ + s) * D_ + d] = v;
      }
    }
  }
}

// ---- pass A: denom[bh,k] = sum_i(mask?1:exp(s)); Wg[bh,i,k] = mask?0:exp(s) --
__global__ __launch_bounds__(256) void attn_pass_a(const _Float16* __restrict__ Qh,
                                                   const _Float16* __restrict__ Kh,
                                                   const uint32_t* __restrict__ mw,
                                                   float* __restrict__ denom,
                                                   _Float16* __restrict__ Wg) {
  const int TI = 128, TK = 128, LD = 72, LW = 144;
  __shared__ __align__(16) _Float16 Qs[TI * LD];
  __shared__ __align__(16) _Float16 Ks[TK * LD];
  __shared__ __align__(16) _Float16 Ws[TI * LW];
  __shared__ uint32_t Ms[TI * 4];
  __shared__ float red[4][64];
  const int tid = threadIdx.x, wave = tid >> 6, lane = tid & 63;
  const int l15 = lane & 15, lk = lane >> 4;
  const int wr = wave >> 1, wc = wave & 1;
  const int bh = blockIdx.y, kb = blockIdx.x;
  const _Float16* Qb = Qh + (size_t)bh * S_ * D_;
  const _Float16* Kb = Kh + (size_t)bh * S_ * D_;
  const uint32_t* mrow = mw + (size_t)bh * S_ * 32;
#pragma unroll
  for (int j = 0; j < 4; ++j) {
    int c = tid + j * 256;
    int row = c >> 3, c8 = c & 7;
    *reinterpret_cast<uint4*>(&Ks[row * LD + c8 * 8]) =
        *reinterpret_cast<const uint4*>(&Kb[(size_t)(kb * TK + row) * D_ + c8 * 8]);
  }
  float csum[4] = {0.f, 0.f, 0.f, 0.f};
  for (int ib = 0; ib < S_ / TI; ++ib) {
    __syncthreads();  // B1: Qs free of prev MFMA reads, Ws free of prev copy reads
#pragma unroll
    for (int j = 0; j < 4; ++j) {
      int c = tid + j * 256;
      int row = c >> 3, c8 = c & 7;
      *reinterpret_cast<uint4*>(&Qs[row * LD + c8 * 8]) =
          *reinterpret_cast<const uint4*>(&Qb[(size_t)(ib * TI + row) * D_ + c8 * 8]);
    }
    Ms[tid] = mrow[(size_t)(ib * TI + (tid >> 2)) * 32 + kb * 4 + (tid & 3)];
    Ms[tid + 256] = mrow[(size_t)(ib * TI + 64 + (tid >> 2)) * 32 + kb * 4 + (tid & 3)];
    __syncthreads();  // B2
    f32x4 acc[4][4] = {};
#pragma unroll
    for (int kk = 0; kk < 2; ++kk) {
      f16x8 a[4], b[4];
#pragma unroll
      for (int m = 0; m < 4; ++m)
        a[m] = *reinterpret_cast<const f16x8*>(&Qs[(wr * 64 + m * 16 + l15) * LD + kk * 32 + lk * 8]);
#pragma unroll
      for (int n = 0; n < 4; ++n)
        b[n] = *reinterpret_cast<const f16x8*>(&Ks[(wc * 64 + n * 16 + l15) * LD + kk * 32 + lk * 8]);
#pragma unroll
      for (int m = 0; m < 4; ++m)
#pragma unroll
        for (int n = 0; n < 4; ++n)
          acc[m][n] = __builtin_amdgcn_mfma_f32_16x16x32_f16(a[m], b[n], acc[m][n], 0, 0, 0);
    }
#pragma unroll
    for (int n = 0; n < 4; ++n) {
      int kcol = wc * 64 + n * 16 + l15;
      int kwl = kcol >> 5;
      int kbit = kcol & 31;
      float part = 0.f;
#pragma unroll
      for (int m = 0; m < 4; ++m) {
        int lr0 = wr * 64 + m * 16 + lk * 4;
#pragma unroll
        for (int r = 0; r < 4; ++r) {
          bool msk = (Ms[(lr0 + r) * 4 + kwl] >> kbit) & 1;
          float e = __expf(acc[m][n][r]);  // Q pre-scaled by 1/8
          part += msk ? 1.0f : e;
          Ws[(lr0 + r) * LW + kcol] = msk ? (_Float16)0.f : (_Float16)e;
        }
      }
      csum[n] += part;
    }
    __syncthreads();  // B3: Ws complete
#pragma unroll
    for (int j = 0; j < 8; ++j) {
      int c = tid + j * 256;
      int row = c >> 4, col8 = c & 15;
      *reinterpret_cast<uint4*>(
          &Wg[((size_t)bh << 20) + (size_t)(ib * TI + row) * 1024 + kb * TK + col8 * 8]) =
          *reinterpret_cast<const uint4*>(&Ws[row * LW + col8 * 8]);
    }
  }
#pragma unroll
  for (int n = 0; n < 4; ++n) {
    float v = csum[n];
    v += __shfl_xor(v, 16);
    v += __shfl_xor(v, 32);
    csum[n] = v;
  }
  __syncthreads();
  if (lane < 16) {
#pragma unroll
    for (int n = 0; n < 4; ++n) red[wave][n * 16 + l15] = csum[n];
  }
  __syncthreads();
  if (tid < 128) {
    int wcx = tid >> 6, col = tid & 63;
    denom[(size_t)bh * S_ + kb * TK + wcx * 64 + col] = red[wcx][col] + red[wcx + 2][col];
  }
}

// ---------------- V' = V / denom (in place) -----------------------------------
__global__ __launch_bounds__(256) void vscale(_Float16* __restrict__ Vt,
                                              const float* __restrict__ Dn) {
  size_t e = ((size_t)blockIdx.x * 256 + threadIdx.x) * 8;  // over BH*D*S
  int bh = (int)(e >> 16);
  int s = (int)(e & (S_ - 1));
  uint4 raw = *reinterpret_cast<uint4*>(Vt + e);
  _Float16* h = reinterpret_cast<_Float16*>(&raw);
  const float* dp = Dn + (size_t)bh * S_ + s;
#pragma unroll
  for (int j = 0; j < 8; ++j) h[j] = (_Float16)((float)h[j] / dp[j]);
  *reinterpret_cast<uint4*>(Vt + e) = raw;
}

// ---------------- PV GEMM: An[i,d] = sum_k Wg[i,k] * V'[d,k] ------------------
__global__ __launch_bounds__(256) void gemm_pv(const _Float16* __restrict__ Wg,
                                               const _Float16* __restrict__ Vp,
                                               _Float16* __restrict__ An) {
  const int BK = 64;
  __shared__ __align__(16) _Float16 As[128 * BK];  // XOR-swizzled 16B slots
  __shared__ __align__(16) _Float16 Bs[64 * BK];
  const int tid = threadIdx.x, wave = tid >> 6, lane = tid & 63;
  const int l15 = lane & 15, lk = lane >> 4;
  const int wr = wave >> 1, wc = wave & 1;
  const int ibl = blockIdx.x, bh = blockIdx.y;
  const _Float16* Wb = Wg + ((size_t)bh << 20) + (size_t)ibl * 128 * 1024;
  const _Float16* Vb = Vp + ((size_t)bh << 16);
  f32x4 acc[4][2] = {};
  for (int kt = 0; kt < 16; ++kt) {
#pragma unroll
    for (int j = 0; j < 4; ++j) {  // A: 128 rows x 8 slots
      int c = tid + j * 256;
      int row = c >> 3, slot = c & 7;
      int gs = slot ^ (row & 7);  // pre-swizzled source
      gl_lds16(&Wb[(size_t)row * 1024 + kt * BK + gs * 8], &As[c * 8]);
    }
#pragma unroll
    for (int j = 0; j < 2; ++j) {  // B: 64 rows x 8 slots
      int c = tid + j * 256;
      int row = c >> 3, slot = c & 7;
      int gs = slot ^ (row & 7);
      gl_lds16(&Vb[(size_t)row * 1024 + kt * BK + gs * 8], &Bs[c * 8]);
    }
    __syncthreads();
#pragma unroll
    for (int kk = 0; kk < 2; ++kk) {
      f16x8 a[4], b[2];
#pragma unroll
      for (int m = 0; m < 4; ++m) {
        int row = wr * 64 + m * 16 + l15;
        int slot = (kk * 4 + lk) ^ (row & 7);
        a[m] = *reinterpret_cast<const f16x8*>(&As[row * BK + slot * 8]);
      }
#pragma unroll
      for (int n = 0; n < 2; ++n) {
        int row = wc * 32 + n * 16 + l15;
        int slot = (kk * 4 + lk) ^ (row & 7);
        b[n] = *reinterpret_cast<const f16x8*>(&Bs[row * BK + slot * 8]);
      }
#pragma unroll
      for (int m = 0; m < 4; ++m)
#pragma unroll
        for (int n = 0; n < 2; ++n)
          acc[m][n] = __builtin_amdgcn_mfma_f32_16x16x32_f16(a[m], b[n], acc[m][n], 0, 0, 0);
    }
    __syncthreads();
  }
  const int b_ = bh >> 4, h = bh & 15;
#pragma unroll
  for (int m = 0; m < 4; ++m) {
#pragma unroll
    for (int n = 0; n < 2; ++n) {
#pragma unroll
      for (int r = 0; r < 4; ++r) {
        int i = ibl * 128 + wr * 64 + m * 16 + lk * 4 + r;
        int d = wc * 32 + n * 16 + l15;
        An[((size_t)(b_ * S_ + i)) * E_ + h * D_ + d] = (_Float16)acc[m][n][r];
      }
    }
  }
}

// ---------------- output GEMM: out[m,n] = sum_k An[m,k]*Wo[n,k], fp32 out -----
__global__ __launch_bounds__(256) void gemm_out(const _Float16* __restrict__ An,
                                               const _Float16* __restrict__ Bw,
                                               float* __restrict__ outp) {
  const int K = 1024, BM = 128, BN = 64, BK = 32;
  __shared__ __align__(16) _Float16 As[BM * BK];
  __shared__ __align__(16) _Float16 Bs[BN * BK];
  const int tid = threadIdx.x, wave = tid >> 6, lane = tid & 63;
  const int l15 = lane & 15, lk = lane >> 4;
  const int wr = wave >> 1, wc = wave & 1;
  const int mb = blockIdx.x, nb = blockIdx.y;
  const int srow = (lane >> 2), scol = (lane & 3) * 8;
  f32x4 acc[4][2] = {};
  for (int kt = 0; kt < K / BK; ++kt) {
#pragma unroll
    for (int c = 0; c < 2; ++c) {
      int ch = wave * 2 + c;
      int row = ch * 16 + srow;
      gl_lds16(&An[(size_t)(mb * BM + row) * K + kt * BK + scol], &As[ch * 512]);
    }
    {
      int row = wave * 16 + srow;
      gl_lds16(&Bw[(size_t)(nb * BN + row) * K + kt * BK + scol], &Bs[wave * 512]);
    }
    __syncthreads();
    f16x8 a[4], b[2];
#pragma unroll
    for (int m = 0; m < 4; ++m)
      a[m] = *reinterpret_cast<const f16x8*>(&As[(wr * 64 + m * 16 + l15) * BK + lk * 8]);
#pragma unroll
    for (int n = 0; n < 2; ++n)
      b[n] = *reinterpret_cast<const f16x8*>(&Bs[(wc * 32 + n * 16 + l15) * BK + lk * 8]);
#pragma unroll
    for (int m = 0; m < 4; ++m)
#pragma unroll
      for (int n = 0; n < 2; ++n)
        acc[m][n] = __builtin_amdgcn_mfma_f32_16x16x32_f16(a[m], b[n], acc[m][n], 0, 0, 0);
    __syncthreads();
  }
#pragma unroll
  for (int m = 0; m < 4; ++m) {
#pragma unroll
    for (int n = 0; n < 2; ++n) {
#pragma unroll
      for (int r = 0; r < 4; ++r) {
        int gm = mb * BM + wr * 64 + m * 16 + lk * 4 + r;
        int gn = nb * BN + wc * 32 + n * 16 + l15;
        outp[(size_t)gm * 1024 + gn] = acc[m][n][r];
      }
    }
  }
}

extern "C" void kernel_launch(void* const* d_in, const int* in_sizes, int n_in,
                              void* d_out, int out_size, void* d_ws, size_t ws_size,
                              hipStream_t stream) {
  const float* q = (const float*)d_in[0];
  const float* k = (const float*)d_in[1];
  const float* v = (const float*)d_in[2];
  const int* am = (const int*)d_in[3];
  const int* kpm = (const int*)d_in[4];
  const float* Wq = (const float*)d_in[5];
  const float* Wk = (const float*)d_in[6];
  const float* Wv = (const float*)d_in[7];
  const float* Wo = (const float*)d_in[8];
  float* out = (float*)d_out;

  _Float16* cvt = (_Float16*)d_ws;        // 16M f16 = 32 MiB
  _Float16* qkv = cvt;                    // q,k,v @ 0,4M,8M elems
  _Float16* wts = cvt + (12u << 20);      // Wq,Wk,Wv @ 12,13,14M elems
  _Float16* wob = cvt + (15u << 20);      // Wo @ 15M elems
  uint8_t* ws = (uint8_t*)d_ws;
  _Float16* Qh = (_Float16*)(ws + (32ull << 20));  // [BH,S,D] 8 MiB (pre-scaled /8)
  _Float16* Kh = (_Float16*)(ws + (40ull << 20));  // [BH,S,D] 8 MiB
  _Float16* Vt = (_Float16*)(ws + (48ull << 20));  // [BH,D,S] 8 MiB (later /denom)
  uint32_t* MW = (uint32_t*)(ws + (56ull << 20));  // packed mask 8 MiB
  float* Dn = (float*)(ws + (64ull << 20));        // denom [BH,S] 256 KiB
  _Float16* Wg = (_Float16*)(ws + (80ull << 20));  // [BH,S,S] unnorm weights 128 MiB
  _Float16* An = qkv;                              // reuse q region (dead after proj)

  cvt_f16<<<16384, 256, 0, stream>>>(q, k, v, Wq, Wk, Wv, Wo, cvt);
  pack_mask<<<65536, 256, 0, stream>>>(am, kpm, MW);
  gemm_proj<<<dim3(32, 8, 3), 256, 0, stream>>>(qkv, wts, Qh, Vt);
  attn_pass_a<<<dim3(8, 64), 256, 0, stream>>>(Qh, Kh, MW, Dn, Wg);
  vscale<<<2048, 256, 0, stream>>>(Vt, Dn);
  gemm_pv<<<dim3(8, 64), 256, 0, stream>>>(Wg, Vt, An);
  gemm_out<<<dim3(32, 16), 256, 0, stream>>>(An, wob, out);
}

// Round 5
// 565.377 us; speedup vs baseline: 1.4530x; 1.0031x over previous
//
#include <hip/hip_runtime.h>
#include <stdint.h>

#define S_ 1024
#define E_ 1024
#define H_ 16
#define D_ 64
#define BH_ 64

typedef __attribute__((ext_vector_type(4))) float f32x4;
typedef __attribute__((ext_vector_type(8))) _Float16 f16x8;

__device__ __forceinline__ void gl_lds16(const void* g, void* l) {
  __builtin_amdgcn_global_load_lds((__attribute__((address_space(1))) void*)(g),
                                   (__attribute__((address_space(3))) void*)(l), 16, 0, 0);
}

// ---------------- fp32 -> fp16 convert: q,k,v,Wq,Wk,Wv,Wo into one region -----
__global__ __launch_bounds__(256) void cvt_f16(const float* __restrict__ q,
                                               const float* __restrict__ k,
                                               const float* __restrict__ v,
                                               const float* __restrict__ wq,
                                               const float* __restrict__ wk,
                                               const float* __restrict__ wv,
                                               const float* __restrict__ wo,
                                               _Float16* __restrict__ dst) {
  size_t i = ((size_t)blockIdx.x * 256 + threadIdx.x) * 4;
  const size_t M4 = 4u << 20, M1 = 1u << 20;
  const float* src;
  size_t off;
  if (i < M4) { src = q; off = i; }
  else if (i < 2 * M4) { src = k; off = i - M4; }
  else if (i < 3 * M4) { src = v; off = i - 2 * M4; }
  else if (i < 3 * M4 + M1) { src = wq; off = i - 3 * M4; }
  else if (i < 3 * M4 + 2 * M1) { src = wk; off = i - (3 * M4 + M1); }
  else if (i < 3 * M4 + 3 * M1) { src = wv; off = i - (3 * M4 + 2 * M1); }
  else { src = wo; off = i - (3 * M4 + 3 * M1); }
  float4 f = *reinterpret_cast<const float4*>(src + off);
  _Float16 h[4];
  h[0] = (_Float16)f.x; h[1] = (_Float16)f.y; h[2] = (_Float16)f.z; h[3] = (_Float16)f.w;
  *reinterpret_cast<uint2*>(dst + i) = *reinterpret_cast<uint2*>(h);
}

// ---------------- mask bit-pack: bit = attn_mask || key_padding_mask ----------
__global__ __launch_bounds__(256) void pack_mask(const int* __restrict__ am,
                                                 const int* __restrict__ kpm,
                                                 uint32_t* __restrict__ mw) {
  size_t t = (size_t)blockIdx.x * 256 + threadIdx.x;  // handles elems [4t,4t+4)
  size_t f = t * 4;
  int k = (int)(f & (S_ - 1));
  int b = (int)(f >> 24);
  int4 a = *reinterpret_cast<const int4*>(am + f);
  int4 kp = *reinterpret_cast<const int4*>(kpm + (size_t)b * S_ + k);
  uint32_t nib = (uint32_t)((a.x | kp.x) != 0) | ((uint32_t)((a.y | kp.y) != 0) << 1) |
                 ((uint32_t)((a.z | kp.z) != 0) << 2) | ((uint32_t)((a.w | kp.w) != 0) << 3);
  uint32_t v = nib << ((threadIdx.x & 7) * 4);
  v |= __shfl_xor(v, 1);
  v |= __shfl_xor(v, 2);
  v |= __shfl_xor(v, 4);
  if ((threadIdx.x & 7) == 0) mw[t >> 3] = v;
}

// ---------------- fused projection GEMM: z=0 Q(/8), z=1 K, z=2 V(transposed) --
__global__ __launch_bounds__(256) void gemm_proj(const _Float16* __restrict__ qkv,
                                                 const _Float16* __restrict__ wts,
                                                 _Float16* __restrict__ QKo,
                                                 _Float16* __restrict__ Vt) {
  const int K = 1024, BM = 128, BK = 32;
  __shared__ __align__(16) _Float16 As[BM * BK];
  __shared__ __align__(16) _Float16 Bs[BM * BK];
  const int tid = threadIdx.x, wave = tid >> 6, lane = tid & 63;
  const int l15 = lane & 15, lk = lane >> 4;
  const int wr = wave >> 1, wc = wave & 1;
  const int mb = blockIdx.x, nb = blockIdx.y, z = blockIdx.z;
  const _Float16* A = qkv + (size_t)z * (4u << 20);
  const _Float16* Bw = wts + (size_t)z * (1u << 20);
  const int srow = (lane >> 2);
  const int scol = (lane & 3) * 8;
  f32x4 acc[4][4] = {};
  for (int kt = 0; kt < K / BK; ++kt) {
#pragma unroll
    for (int c = 0; c < 2; ++c) {
      int ch = wave * 2 + c;
      int row = ch * 16 + srow;
      gl_lds16(&A[(size_t)(mb * BM + row) * K + kt * BK + scol], &As[ch * 512]);
      gl_lds16(&Bw[(size_t)(nb * BM + row) * K + kt * BK + scol], &Bs[ch * 512]);
    }
    __syncthreads();
    f16x8 a[4], b[4];
#pragma unroll
    for (int m = 0; m < 4; ++m)
      a[m] = *reinterpret_cast<const f16x8*>(&As[(wr * 64 + m * 16 + l15) * BK + lk * 8]);
#pragma unroll
    for (int n = 0; n < 4; ++n)
      b[n] = *reinterpret_cast<const f16x8*>(&Bs[(wc * 64 + n * 16 + l15) * BK + lk * 8]);
#pragma unroll
    for (int m = 0; m < 4; ++m)
#pragma unroll
      for (int n = 0; n < 4; ++n)
        acc[m][n] = __builtin_amdgcn_mfma_f32_16x16x32_f16(a[m], b[n], acc[m][n], 0, 0, 0);
    __syncthreads();
  }
  const float qs = (z == 0) ? 0.125f : 1.0f;
#pragma unroll
  for (int m = 0; m < 4; ++m) {
#pragma unroll
    for (int n = 0; n < 4; ++n) {
#pragma unroll
      for (int r = 0; r < 4; ++r) {
        int gm = mb * BM + wr * 64 + m * 16 + lk * 4 + r;
        int gn = nb * BM + wc * 64 + n * 16 + l15;
        int bb = gm >> 10, s = gm & 1023, h = gn >> 6, d = gn & 63;
        int bh = bb * 16 + h;
        _Float16 v = (_Float16)(acc[m][n][r] * qs);
        if (z == 2)
          Vt[((size_t)bh * D_ + d) * S_ + s] = v;
        else
          QKo[(size_t)z * (4u << 20) + ((size_t)bh * S_ + s) * D_ + d] = v;
      }
    }
  }
}

// ---- attn_denom: denom[bh,k] = sum_i (mask ? 1 : exp(QK/8)) ------------------
__global__ __launch_bounds__(256) void attn_denom(const _Float16* __restrict__ Qh,
                                                  const _Float16* __restrict__ Kh,
                                                  const uint32_t* __restrict__ mw,
                                                  float* __restrict__ denom) {
  const int TI = 128, TK = 128, LD = 72;
  __shared__ __align__(16) _Float16 Qs[TI * LD];
  __shared__ __align__(16) _Float16 Ks[TK * LD];
  __shared__ uint32_t Ms[TI * 4];
  __shared__ float red[4][64];
  const int tid = threadIdx.x, wave = tid >> 6, lane = tid & 63;
  const int l15 = lane & 15, lk = lane >> 4;
  const int wr = wave >> 1, wc = wave & 1;
  const int bh = blockIdx.y, kb = blockIdx.x;
  const _Float16* Qb = Qh + (size_t)bh * S_ * D_;
  const _Float16* Kb = Kh + (size_t)bh * S_ * D_;
  const uint32_t* mrow = mw + (size_t)bh * S_ * 32;
#pragma unroll
  for (int j = 0; j < 4; ++j) {
    int c = tid + j * 256;
    int row = c >> 3, c8 = c & 7;
    *reinterpret_cast<uint4*>(&Ks[row * LD + c8 * 8]) =
        *reinterpret_cast<const uint4*>(&Kb[(size_t)(kb * TK + row) * D_ + c8 * 8]);
  }
  float csum[4] = {0.f, 0.f, 0.f, 0.f};
  for (int ib = 0; ib < S_ / TI; ++ib) {
    __syncthreads();  // Qs/Ms free of previous iteration's readers
#pragma unroll
    for (int j = 0; j < 4; ++j) {
      int c = tid + j * 256;
      int row = c >> 3, c8 = c & 7;
      *reinterpret_cast<uint4*>(&Qs[row * LD + c8 * 8]) =
          *reinterpret_cast<const uint4*>(&Qb[(size_t)(ib * TI + row) * D_ + c8 * 8]);
    }
    Ms[tid] = mrow[(size_t)(ib * TI + (tid >> 2)) * 32 + kb * 4 + (tid & 3)];
    Ms[tid + 256] = mrow[(size_t)(ib * TI + 64 + (tid >> 2)) * 32 + kb * 4 + (tid & 3)];
    __syncthreads();
    f32x4 acc[4][4] = {};
#pragma unroll
    for (int kk = 0; kk < 2; ++kk) {
      f16x8 a[4], b[4];
#pragma unroll
      for (int m = 0; m < 4; ++m)
        a[m] = *reinterpret_cast<const f16x8*>(&Qs[(wr * 64 + m * 16 + l15) * LD + kk * 32 + lk * 8]);
#pragma unroll
      for (int n = 0; n < 4; ++n)
        b[n] = *reinterpret_cast<const f16x8*>(&Ks[(wc * 64 + n * 16 + l15) * LD + kk * 32 + lk * 8]);
#pragma unroll
      for (int m = 0; m < 4; ++m)
#pragma unroll
        for (int n = 0; n < 4; ++n)
          acc[m][n] = __builtin_amdgcn_mfma_f32_16x16x32_f16(a[m], b[n], acc[m][n], 0, 0, 0);
    }
#pragma unroll
    for (int n = 0; n < 4; ++n) {
      int kcol = wc * 64 + n * 16 + l15;
      int kwl = kcol >> 5;
      int kbit = kcol & 31;
      float part = 0.f;
#pragma unroll
      for (int m = 0; m < 4; ++m) {
        int lr0 = wr * 64 + m * 16 + lk * 4;
#pragma unroll
        for (int r = 0; r < 4; ++r) {
          bool msk = (Ms[(lr0 + r) * 4 + kwl] >> kbit) & 1;
          float e = __expf(acc[m][n][r]);  // Q pre-scaled by 1/8
          part += msk ? 1.0f : e;
        }
      }
      csum[n] += part;
    }
  }
#pragma unroll
  for (int n = 0; n < 4; ++n) {
    float v = csum[n];
    v += __shfl_xor(v, 16);
    v += __shfl_xor(v, 32);
    csum[n] = v;
  }
  __syncthreads();
  if (lane < 16) {
#pragma unroll
    for (int n = 0; n < 4; ++n) red[wave][n * 16 + l15] = csum[n];
  }
  __syncthreads();
  if (tid < 128) {
    int wcx = tid >> 6, col = tid & 63;
    denom[(size_t)bh * S_ + kb * TK + wcx * 64 + col] = red[wcx][col] + red[wcx + 2][col];
  }
}

// ---------------- V' = V / denom (in place) -----------------------------------
__global__ __launch_bounds__(256) void vscale(_Float16* __restrict__ Vt,
                                              const float* __restrict__ Dn) {
  size_t e = ((size_t)blockIdx.x * 256 + threadIdx.x) * 8;  // over BH*D*S
  int bh = (int)(e >> 16);
  int s = (int)(e & (S_ - 1));
  uint4 raw = *reinterpret_cast<uint4*>(Vt + e);
  _Float16* h = reinterpret_cast<_Float16*>(&raw);
  const float* dp = Dn + (size_t)bh * S_ + s;
#pragma unroll
  for (int j = 0; j < 8; ++j) h[j] = (_Float16)((float)h[j] / dp[j]);
  *reinterpret_cast<uint4*>(Vt + e) = raw;
}

// ---- attn_pv: An[i,d] = sum_k (mask?0:exp(QK/8)) * V'[d,k] (fused, no Wg) ----
__global__ __launch_bounds__(256) void attn_pv(const _Float16* __restrict__ Qh,
                                               const _Float16* __restrict__ Kh,
                                               const _Float16* __restrict__ Vp,
                                               const uint32_t* __restrict__ mw,
                                               _Float16* __restrict__ An) {
  const int TI = 128, TK = 128, LD = 72, LW = 136;
  __shared__ __align__(16) _Float16 Qs[TI * LD];   // 18 KB
  __shared__ __align__(16) _Float16 Ks[TK * LD];   // 18 KB
  __shared__ __align__(16) _Float16 Ws[TI * LW];   // 34 KB
  __shared__ uint32_t Ms[TI * 4];                  // 2 KB
  const int tid = threadIdx.x, wave = tid >> 6, lane = tid & 63;
  const int l15 = lane & 15, lk = lane >> 4;
  const int wr = wave >> 1, wc = wave & 1;
  const int bh = blockIdx.y, ib = blockIdx.x;
  const _Float16* Qb = Qh + (size_t)bh * S_ * D_;
  const _Float16* Kb = Kh + (size_t)bh * S_ * D_;
  const _Float16* Vb = Vp + ((size_t)bh << 16);
  const uint32_t* mrow = mw + (size_t)bh * S_ * 32;
  // stage Q once
#pragma unroll
  for (int j = 0; j < 4; ++j) {
    int c = tid + j * 256;
    int row = c >> 3, c8 = c & 7;
    *reinterpret_cast<uint4*>(&Qs[row * LD + c8 * 8]) =
        *reinterpret_cast<const uint4*>(&Qb[(size_t)(ib * TI + row) * D_ + c8 * 8]);
  }
  f32x4 acc2[4][2] = {};
  for (int kt = 0; kt < S_ / TK; ++kt) {
    __syncthreads();  // B1: prev PV done (Ws,Ks free); Qs staged (first iter)
#pragma unroll
    for (int j = 0; j < 4; ++j) {
      int c = tid + j * 256;
      int row = c >> 3, c8 = c & 7;
      *reinterpret_cast<uint4*>(&Ks[row * LD + c8 * 8]) =
          *reinterpret_cast<const uint4*>(&Kb[(size_t)(kt * TK + row) * D_ + c8 * 8]);
    }
    Ms[tid] = mrow[(size_t)(ib * TI + (tid >> 2)) * 32 + kt * 4 + (tid & 3)];
    Ms[tid + 256] = mrow[(size_t)(ib * TI + 64 + (tid >> 2)) * 32 + kt * 4 + (tid & 3)];
    __syncthreads();  // B2: Ks/Ms visible
    f32x4 acc[4][4] = {};
#pragma unroll
    for (int kk = 0; kk < 2; ++kk) {
      f16x8 a[4], b[4];
#pragma unroll
      for (int m = 0; m < 4; ++m)
        a[m] = *reinterpret_cast<const f16x8*>(&Qs[(wr * 64 + m * 16 + l15) * LD + kk * 32 + lk * 8]);
#pragma unroll
      for (int n = 0; n < 4; ++n)
        b[n] = *reinterpret_cast<const f16x8*>(&Ks[(wc * 64 + n * 16 + l15) * LD + kk * 32 + lk * 8]);
#pragma unroll
      for (int m = 0; m < 4; ++m)
#pragma unroll
        for (int n = 0; n < 4; ++n)
          acc[m][n] = __builtin_amdgcn_mfma_f32_16x16x32_f16(a[m], b[n], acc[m][n], 0, 0, 0);
    }
    // masked exp -> Ws (unnormalized; denom folded into V')
#pragma unroll
    for (int n = 0; n < 4; ++n) {
      int kcol = wc * 64 + n * 16 + l15;
      int kwl = kcol >> 5;
      int kbit = kcol & 31;
#pragma unroll
      for (int m = 0; m < 4; ++m) {
        int lr0 = wr * 64 + m * 16 + lk * 4;
#pragma unroll
        for (int r = 0; r < 4; ++r) {
          bool msk = (Ms[(lr0 + r) * 4 + kwl] >> kbit) & 1;
          float e = __expf(acc[m][n][r]);
          Ws[(lr0 + r) * LW + kcol] = msk ? (_Float16)0.f : (_Float16)e;
        }
      }
    }
    __syncthreads();  // B3: Ws complete
    // PV: acc2 += Ws(i,k) x V'(d,k); V' fragments direct from L2
#pragma unroll
    for (int kk = 0; kk < 4; ++kk) {
      f16x8 a2[4], b2[2];
#pragma unroll
      for (int m = 0; m < 4; ++m)
        a2[m] = *reinterpret_cast<const f16x8*>(&Ws[(wr * 64 + m * 16 + l15) * LW + kk * 32 + lk * 8]);
#pragma unroll
      for (int n = 0; n < 2; ++n)
        b2[n] = *reinterpret_cast<const f16x8*>(
            &Vb[(size_t)(wc * 32 + n * 16 + l15) * S_ + kt * TK + kk * 32 + lk * 8]);
#pragma unroll
      for (int m = 0; m < 4; ++m)
#pragma unroll
        for (int n = 0; n < 2; ++n)
          acc2[m][n] = __builtin_amdgcn_mfma_f32_16x16x32_f16(a2[m], b2[n], acc2[m][n], 0, 0, 0);
    }
  }
  const int b_ = bh >> 4, h = bh & 15;
#pragma unroll
  for (int m = 0; m < 4; ++m) {
#pragma unroll
    for (int n = 0; n < 2; ++n) {
#pragma unroll
      for (int r = 0; r < 4; ++r) {
        int i = ib * TI + wr * 64 + m * 16 + lk * 4 + r;
        int d = wc * 32 + n * 16 + l15;
        An[((size_t)(b_ * S_ + i)) * E_ + h * D_ + d] = (_Float16)acc2[m][n][r];
      }
    }
  }
}

// ---------------- output GEMM: out[m,n] = sum_k An[m,k]*Wo[n,k], fp32 out -----
__global__ __launch_bounds__(256) void gemm_out(const _Float16* __restrict__ An,
                                               const _Float16* __restrict__ Bw,
                                               float* __restrict__ outp) {
  const int K = 1024, BM = 128, BN = 64, BK = 32;
  __shared__ __align__(16) _Float16 As[BM * BK];
  __shared__ __align__(16) _Float16 Bs[BN * BK];
  const int tid = threadIdx.x, wave = tid >> 6, lane = tid & 63;
  const int l15 = lane & 15, lk = lane >> 4;
  const int wr = wave >> 1, wc = wave & 1;
  const int mb = blockIdx.x, nb = blockIdx.y;
  const int srow = (lane >> 2), scol = (lane & 3) * 8;
  f32x4 acc[4][2] = {};
  for (int kt = 0; kt < K / BK; ++kt) {
#pragma unroll
    for (int c = 0; c < 2; ++c) {
      int ch = wave * 2 + c;
      int row = ch * 16 + srow;
      gl_lds16(&An[(size_t)(mb * BM + row) * K + kt * BK + scol], &As[ch * 512]);
    }
    {
      int row = wave * 16 + srow;
      gl_lds16(&Bw[(size_t)(nb * BN + row) * K + kt * BK + scol], &Bs[wave * 512]);
    }
    __syncthreads();
    f16x8 a[4], b[2];
#pragma unroll
    for (int m = 0; m < 4; ++m)
      a[m] = *reinterpret_cast<const f16x8*>(&As[(wr * 64 + m * 16 + l15) * BK + lk * 8]);
#pragma unroll
    for (int n = 0; n < 2; ++n)
      b[n] = *reinterpret_cast<const f16x8*>(&Bs[(wc * 32 + n * 16 + l15) * BK + lk * 8]);
#pragma unroll
    for (int m = 0; m < 4; ++m)
#pragma unroll
      for (int n = 0; n < 2; ++n)
        acc[m][n] = __builtin_amdgcn_mfma_f32_16x16x32_f16(a[m], b[n], acc[m][n], 0, 0, 0);
    __syncthreads();
  }
#pragma unroll
  for (int m = 0; m < 4; ++m) {
#pragma unroll
    for (int n = 0; n < 2; ++n) {
#pragma unroll
      for (int r = 0; r < 4; ++r) {
        int gm = mb * BM + wr * 64 + m * 16 + lk * 4 + r;
        int gn = nb * BN + wc * 32 + n * 16 + l15;
        outp[(size_t)gm * 1024 + gn] = acc[m][n][r];
      }
    }
  }
}

extern "C" void kernel_launch(void* const* d_in, const int* in_sizes, int n_in,
                              void* d_out, int out_size, void* d_ws, size_t ws_size,
                              hipStream_t stream) {
  const float* q = (const float*)d_in[0];
  const float* k = (const float*)d_in[1];
  const float* v = (const float*)d_in[2];
  const int* am = (const int*)d_in[3];
  const int* kpm = (const int*)d_in[4];
  const float* Wq = (const float*)d_in[5];
  const float* Wk = (const float*)d_in[6];
  const float* Wv = (const float*)d_in[7];
  const float* Wo = (const float*)d_in[8];
  float* out = (float*)d_out;

  _Float16* cvt = (_Float16*)d_ws;        // 16M f16 = 32 MiB
  _Float16* qkv = cvt;                    // q,k,v @ 0,4M,8M elems
  _Float16* wts = cvt + (12u << 20);      // Wq,Wk,Wv @ 12,13,14M elems
  _Float16* wob = cvt + (15u << 20);      // Wo @ 15M elems
  uint8_t* ws = (uint8_t*)d_ws;
  _Float16* Qh = (_Float16*)(ws + (32ull << 20));  // [BH,S,D] 8 MiB (pre-scaled /8)
  _Float16* Kh = (_Float16*)(ws + (40ull << 20));  // [BH,S,D] 8 MiB
  _Float16* Vt = (_Float16*)(ws + (48ull << 20));  // [BH,D,S] 8 MiB (later /denom)
  uint32_t* MW = (uint32_t*)(ws + (56ull << 20));  // packed mask 8 MiB
  float* Dn = (float*)(ws + (64ull << 20));        // denom [BH,S] 256 KiB
  _Float16* An = qkv;                              // reuse q region (dead after proj)

  cvt_f16<<<16384, 256, 0, stream>>>(q, k, v, Wq, Wk, Wv, Wo, cvt);
  pack_mask<<<65536, 256, 0, stream>>>(am, kpm, MW);
  gemm_proj<<<dim3(32, 8, 3), 256, 0, stream>>>(qkv, wts, Qh, Vt);
  attn_denom<<<dim3(8, 64), 256, 0, stream>>>(Qh, Kh, MW, Dn);
  vscale<<<2048, 256, 0, stream>>>(Vt, Dn);
  attn_pv<<<dim3(8, 64), 256, 0, stream>>>(Qh, Kh, Vt, MW, An);
  gemm_out<<<dim3(32, 16), 256, 0, stream>>>(An, wob, out);
}

// Round 7
// 562.223 us; speedup vs baseline: 1.4612x; 1.0056x over previous
//
#include <hip/hip_runtime.h>
#include <stdint.h>

#define S_ 1024
#define E_ 1024
#define H_ 16
#define D_ 64
#define BH_ 64

typedef __attribute__((ext_vector_type(4))) float f32x4;
typedef __attribute__((ext_vector_type(8))) _Float16 f16x8;

__device__ __forceinline__ void gl_lds16(const void* g, void* l) {
  __builtin_amdgcn_global_load_lds((__attribute__((address_space(1))) void*)(g),
                                   (__attribute__((address_space(3))) void*)(l), 16, 0, 0);
}

// ---------------- fp32 -> fp16 convert: q,k,v,Wq,Wk,Wv,Wo into one region -----
__global__ __launch_bounds__(256) void cvt_f16(const float* __restrict__ q,
                                               const float* __restrict__ k,
                                               const float* __restrict__ v,
                                               const float* __restrict__ wq,
                                               const float* __restrict__ wk,
                                               const float* __restrict__ wv,
                                               const float* __restrict__ wo,
                                               _Float16* __restrict__ dst) {
  size_t i = ((size_t)blockIdx.x * 256 + threadIdx.x) * 4;
  const size_t M4 = 4u << 20, M1 = 1u << 20;
  const float* src;
  size_t off;
  if (i < M4) { src = q; off = i; }
  else if (i < 2 * M4) { src = k; off = i - M4; }
  else if (i < 3 * M4) { src = v; off = i - 2 * M4; }
  else if (i < 3 * M4 + M1) { src = wq; off = i - 3 * M4; }
  else if (i < 3 * M4 + 2 * M1) { src = wk; off = i - (3 * M4 + M1); }
  else if (i < 3 * M4 + 3 * M1) { src = wv; off = i - (3 * M4 + 2 * M1); }
  else { src = wo; off = i - (3 * M4 + 3 * M1); }
  float4 f = *reinterpret_cast<const float4*>(src + off);
  _Float16 h[4];
  h[0] = (_Float16)f.x; h[1] = (_Float16)f.y; h[2] = (_Float16)f.z; h[3] = (_Float16)f.w;
  *reinterpret_cast<uint2*>(dst + i) = *reinterpret_cast<uint2*>(h);
}

// ---------------- mask bit-pack: bit = attn_mask || key_padding_mask ----------
__global__ __launch_bounds__(256) void pack_mask(const int* __restrict__ am,
                                                 const int* __restrict__ kpm,
                                                 uint32_t* __restrict__ mw) {
  size_t t = (size_t)blockIdx.x * 256 + threadIdx.x;  // handles elems [4t,4t+4)
  size_t f = t * 4;
  int k = (int)(f & (S_ - 1));
  int b = (int)(f >> 24);
  int4 a = *reinterpret_cast<const int4*>(am + f);
  int4 kp = *reinterpret_cast<const int4*>(kpm + (size_t)b * S_ + k);
  uint32_t nib = (uint32_t)((a.x | kp.x) != 0) | ((uint32_t)((a.y | kp.y) != 0) << 1) |
                 ((uint32_t)((a.z | kp.z) != 0) << 2) | ((uint32_t)((a.w | kp.w) != 0) << 3);
  uint32_t v = nib << ((threadIdx.x & 7) * 4);
  v |= __shfl_xor(v, 1);
  v |= __shfl_xor(v, 2);
  v |= __shfl_xor(v, 4);
  if ((threadIdx.x & 7) == 0) mw[t >> 3] = v;
}

// ---------------- fused projection GEMM: z=0 Q(/8), z=1 K, z=2 V(transposed) --
__global__ __launch_bounds__(256) void gemm_proj(const _Float16* __restrict__ qkv,
                                                 const _Float16* __restrict__ wts,
                                                 _Float16* __restrict__ QKo,
                                                 _Float16* __restrict__ Vt) {
  const int K = 1024, BM = 128, BK = 32;
  __shared__ __align__(16) _Float16 As[BM * BK];
  __shared__ __align__(16) _Float16 Bs[BM * BK];
  __shared__ __align__(16) _Float16 Ts[64 * 136];  // V-transpose staging
  const int tid = threadIdx.x, wave = tid >> 6, lane = tid & 63;
  const int l15 = lane & 15, lk = lane >> 4;
  const int wr = wave >> 1, wc = wave & 1;
  const int mb = blockIdx.x, nb = blockIdx.y, z = blockIdx.z;
  const _Float16* A = qkv + (size_t)z * (4u << 20);
  const _Float16* Bw = wts + (size_t)z * (1u << 20);
  const int srow = (lane >> 2);
  const int scol = (lane & 3) * 8;
  f32x4 acc[4][4] = {};
  for (int kt = 0; kt < K / BK; ++kt) {
#pragma unroll
    for (int c = 0; c < 2; ++c) {
      int ch = wave * 2 + c;
      int row = ch * 16 + srow;
      gl_lds16(&A[(size_t)(mb * BM + row) * K + kt * BK + scol], &As[ch * 512]);
      gl_lds16(&Bw[(size_t)(nb * BM + row) * K + kt * BK + scol], &Bs[ch * 512]);
    }
    __syncthreads();
    f16x8 a[4], b[4];
#pragma unroll
    for (int m = 0; m < 4; ++m)
      a[m] = *reinterpret_cast<const f16x8*>(&As[(wr * 64 + m * 16 + l15) * BK + lk * 8]);
#pragma unroll
    for (int n = 0; n < 4; ++n)
      b[n] = *reinterpret_cast<const f16x8*>(&Bs[(wc * 64 + n * 16 + l15) * BK + lk * 8]);
#pragma unroll
    for (int m = 0; m < 4; ++m)
#pragma unroll
      for (int n = 0; n < 4; ++n)
        acc[m][n] = __builtin_amdgcn_mfma_f32_16x16x32_f16(a[m], b[n], acc[m][n], 0, 0, 0);
    __syncthreads();
  }
  if (z == 2) {
    // coalesced Vt write via LDS transpose, one 64-d head-half at a time
    const int bb = mb >> 3, s0 = (mb & 7) * 128;
    for (int hh = 0; hh < 2; ++hh) {
      __syncthreads();
      if (wc == hh) {
#pragma unroll
        for (int m = 0; m < 4; ++m)
#pragma unroll
          for (int n = 0; n < 4; ++n)
#pragma unroll
            for (int r = 0; r < 4; ++r)
              Ts[(n * 16 + l15) * 136 + wr * 64 + m * 16 + lk * 4 + r] =
                  (_Float16)acc[m][n][r];
      }
      __syncthreads();
      int bh = bb * 16 + nb * 2 + hh;
#pragma unroll
      for (int u = 0; u < 4; ++u) {
        int c = tid + u * 256;
        int d = c >> 4, seg = c & 15;  // 64 rows x 16 uint4 segs = full 128 cols
        *reinterpret_cast<uint4*>(&Vt[(((size_t)bh * 64 + d) << 10) + s0 + seg * 8]) =
            *reinterpret_cast<const uint4*>(&Ts[d * 136 + seg * 8]);
      }
    }
  } else {
    const float qs = (z == 0) ? 0.125f : 1.0f;
#pragma unroll
    for (int m = 0; m < 4; ++m) {
#pragma unroll
      for (int n = 0; n < 4; ++n) {
#pragma unroll
        for (int r = 0; r < 4; ++r) {
          int gm = mb * BM + wr * 64 + m * 16 + lk * 4 + r;
          int gn = nb * BM + wc * 64 + n * 16 + l15;
          int bb = gm >> 10, s = gm & 1023, h = gn >> 6, d = gn & 63;
          int bh = bb * 16 + h;
          QKo[(size_t)z * (4u << 20) + ((size_t)bh * S_ + s) * D_ + d] =
              (_Float16)(acc[m][n][r] * qs);
        }
      }
    }
  }
}

// ---- attn_denom: denom[k] = sum_i (mask?1:exp(QK/8)); fold 1/denom into V ----
__global__ __launch_bounds__(256) void attn_denom(const _Float16* __restrict__ Qh,
                                                  const _Float16* __restrict__ Kh,
                                                  const uint32_t* __restrict__ mw,
                                                  _Float16* __restrict__ Vt) {
  const int TI = 128, TK = 128, LD = 72;
  __shared__ __align__(16) _Float16 Qs[TI * LD];
  __shared__ __align__(16) _Float16 Ks[TK * LD];
  __shared__ uint32_t Ms[TI * 4];
  __shared__ float red[4][64];
  __shared__ float dv[128];
  const int tid = threadIdx.x, wave = tid >> 6, lane = tid & 63;
  const int l15 = lane & 15, lk = lane >> 4;
  const int wr = wave >> 1, wc = wave & 1;
  const int bh = blockIdx.y, kb = blockIdx.x;
  const _Float16* Qb = Qh + (size_t)bh * S_ * D_;
  const _Float16* Kb = Kh + (size_t)bh * S_ * D_;
  const uint32_t* mrow = mw + (size_t)bh * S_ * 32;
#pragma unroll
  for (int j = 0; j < 4; ++j) {
    int c = tid + j * 256;
    int row = c >> 3, c8 = c & 7;
    *reinterpret_cast<uint4*>(&Ks[row * LD + c8 * 8]) =
        *reinterpret_cast<const uint4*>(&Kb[(size_t)(kb * TK + row) * D_ + c8 * 8]);
  }
  float csum[4] = {0.f, 0.f, 0.f, 0.f};
  for (int ib = 0; ib < S_ / TI; ++ib) {
    __syncthreads();
#pragma unroll
    for (int j = 0; j < 4; ++j) {
      int c = tid + j * 256;
      int row = c >> 3, c8 = c & 7;
      *reinterpret_cast<uint4*>(&Qs[row * LD + c8 * 8]) =
          *reinterpret_cast<const uint4*>(&Qb[(size_t)(ib * TI + row) * D_ + c8 * 8]);
    }
    Ms[tid] = mrow[(size_t)(ib * TI + (tid >> 2)) * 32 + kb * 4 + (tid & 3)];
    Ms[tid + 256] = mrow[(size_t)(ib * TI + 64 + (tid >> 2)) * 32 + kb * 4 + (tid & 3)];
    __syncthreads();
    f32x4 acc[4][4] = {};
#pragma unroll
    for (int kk = 0; kk < 2; ++kk) {
      f16x8 a[4], b[4];
#pragma unroll
      for (int m = 0; m < 4; ++m)
        a[m] = *reinterpret_cast<const f16x8*>(&Qs[(wr * 64 + m * 16 + l15) * LD + kk * 32 + lk * 8]);
#pragma unroll
      for (int n = 0; n < 4; ++n)
        b[n] = *reinterpret_cast<const f16x8*>(&Ks[(wc * 64 + n * 16 + l15) * LD + kk * 32 + lk * 8]);
#pragma unroll
      for (int m = 0; m < 4; ++m)
#pragma unroll
        for (int n = 0; n < 4; ++n)
          acc[m][n] = __builtin_amdgcn_mfma_f32_16x16x32_f16(a[m], b[n], acc[m][n], 0, 0, 0);
    }
#pragma unroll
    for (int n = 0; n < 4; ++n) {
      int kcol = wc * 64 + n * 16 + l15;
      int kwl = kcol >> 5;
      int kbit = kcol & 31;
      float part = 0.f;
#pragma unroll
      for (int m = 0; m < 4; ++m) {
        int lr0 = wr * 64 + m * 16 + lk * 4;
#pragma unroll
        for (int r = 0; r < 4; ++r) {
          bool msk = (Ms[(lr0 + r) * 4 + kwl] >> kbit) & 1;
          float e = __expf(acc[m][n][r]);  // Q pre-scaled by 1/8
          part += msk ? 1.0f : e;
        }
      }
      csum[n] += part;
    }
  }
#pragma unroll
  for (int n = 0; n < 4; ++n) {
    float v = csum[n];
    v += __shfl_xor(v, 16);
    v += __shfl_xor(v, 32);
    csum[n] = v;
  }
  __syncthreads();
  if (lane < 16) {
#pragma unroll
    for (int n = 0; n < 4; ++n) red[wave][n * 16 + l15] = csum[n];
  }
  __syncthreads();
  if (tid < 128) dv[tid] = 1.0f / (red[tid >> 6][tid & 63] + red[(tid >> 6) + 2][tid & 63]);
  __syncthreads();
  // scale V[bh][d][kb*128 .. +128] by 1/denom[k] (coalesced 16B per lane)
  _Float16* Vblk = Vt + ((size_t)bh << 16) + kb * TK;
#pragma unroll
  for (int u = 0; u < 4; ++u) {
    int c = tid + u * 256;
    int d = c >> 4, k8 = (c & 15) * 8;
    _Float16* p = Vblk + (size_t)d * 1024 + k8;
    uint4 raw = *reinterpret_cast<uint4*>(p);
    _Float16* h = reinterpret_cast<_Float16*>(&raw);
#pragma unroll
    for (int j = 0; j < 8; ++j) h[j] = (_Float16)((float)h[j] * dv[k8 + j]);
    *reinterpret_cast<uint4*>(p) = raw;
  }
}

// ---- attn_pv: An[i,d] = sum_k (mask?0:exp(QK/8)) * V'[d,k] (fused, no Wg) ----
__global__ __launch_bounds__(256) void attn_pv(const _Float16* __restrict__ Qh,
                                               const _Float16* __restrict__ Kh,
                                               const _Float16* __restrict__ Vp,
                                               const uint32_t* __restrict__ mw,
                                               _Float16* __restrict__ An) {
  const int TI = 128, TK = 128, LD = 72, LW = 136;
  __shared__ __align__(16) _Float16 Qs[TI * LD];   // 18 KB
  __shared__ __align__(16) _Float16 Ks[TK * LD];   // 18 KB
  __shared__ __align__(16) _Float16 Ws[TI * LW];   // 34 KB
  __shared__ uint32_t Ms[TI * 4];                  // 2 KB
  const int tid = threadIdx.x, wave = tid >> 6, lane = tid & 63;
  const int l15 = lane & 15, lk = lane >> 4;
  const int wr = wave >> 1, wc = wave & 1;
  const int bh = blockIdx.y, ib = blockIdx.x;
  const _Float16* Qb = Qh + (size_t)bh * S_ * D_;
  const _Float16* Kb = Kh + (size_t)bh * S_ * D_;
  const _Float16* Vb = Vp + ((size_t)bh << 16);
  const uint32_t* mrow = mw + (size_t)bh * S_ * 32;
  // stage Q once
#pragma unroll
  for (int j = 0; j < 4; ++j) {
    int c = tid + j * 256;
    int row = c >> 3, c8 = c & 7;
    *reinterpret_cast<uint4*>(&Qs[row * LD + c8 * 8]) =
        *reinterpret_cast<const uint4*>(&Qb[(size_t)(ib * TI + row) * D_ + c8 * 8]);
  }
  f32x4 acc2[4][2] = {};
  for (int kt = 0; kt < S_ / TK; ++kt) {
    // prefetch V fragments for this k-tile into registers (hides under QK^T)
    f16x8 vpre[4][2];
#pragma unroll
    for (int kk = 0; kk < 4; ++kk)
#pragma unroll
      for (int n = 0; n < 2; ++n)
        vpre[kk][n] = *reinterpret_cast<const f16x8*>(
            &Vb[(size_t)(wc * 32 + n * 16 + l15) * S_ + kt * TK + kk * 32 + lk * 8]);
    __syncthreads();  // B1: prev PV done (Ws,Ks free)
#pragma unroll
    for (int j = 0; j < 4; ++j) {
      int c = tid + j * 256;
      int row = c >> 3, c8 = c & 7;
      *reinterpret_cast<uint4*>(&Ks[row * LD + c8 * 8]) =
          *reinterpret_cast<const uint4*>(&Kb[(size_t)(kt * TK + row) * D_ + c8 * 8]);
    }
    Ms[tid] = mrow[(size_t)(ib * TI + (tid >> 2)) * 32 + kt * 4 + (tid & 3)];
    Ms[tid + 256] = mrow[(size_t)(ib * TI + 64 + (tid >> 2)) * 32 + kt * 4 + (tid & 3)];
    __syncthreads();  // B2: Ks/Ms visible
    f32x4 acc[4][4] = {};
#pragma unroll
    for (int kk = 0; kk < 2; ++kk) {
      f16x8 a[4], b[4];
#pragma unroll
      for (int m = 0; m < 4; ++m)
        a[m] = *reinterpret_cast<const f16x8*>(&Qs[(wr * 64 + m * 16 + l15) * LD + kk * 32 + lk * 8]);
#pragma unroll
      for (int n = 0; n < 4; ++n)
        b[n] = *reinterpret_cast<const f16x8*>(&Ks[(wc * 64 + n * 16 + l15) * LD + kk * 32 + lk * 8]);
#pragma unroll
      for (int m = 0; m < 4; ++m)
#pragma unroll
        for (int n = 0; n < 4; ++n)
          acc[m][n] = __builtin_amdgcn_mfma_f32_16x16x32_f16(a[m], b[n], acc[m][n], 0, 0, 0);
    }
    // masked exp -> Ws (unnormalized; denom folded into V')
#pragma unroll
    for (int n = 0; n < 4; ++n) {
      int kcol = wc * 64 + n * 16 + l15;
      int kwl = kcol >> 5;
      int kbit = kcol & 31;
#pragma unroll
      for (int m = 0; m < 4; ++m) {
        int lr0 = wr * 64 + m * 16 + lk * 4;
#pragma unroll
        for (int r = 0; r < 4; ++r) {
          bool msk = (Ms[(lr0 + r) * 4 + kwl] >> kbit) & 1;
          float e = __expf(acc[m][n][r]);
          Ws[(lr0 + r) * LW + kcol] = msk ? (_Float16)0.f : (_Float16)e;
        }
      }
    }
    __syncthreads();  // B3: Ws complete
    // PV: acc2 += Ws(i,k) x V'(d,k); V' from registers
#pragma unroll
    for (int kk = 0; kk < 4; ++kk) {
      f16x8 a2[4];
#pragma unroll
      for (int m = 0; m < 4; ++m)
        a2[m] = *reinterpret_cast<const f16x8*>(&Ws[(wr * 64 + m * 16 + l15) * LW + kk * 32 + lk * 8]);
#pragma unroll
      for (int m = 0; m < 4; ++m)
#pragma unroll
        for (int n = 0; n < 2; ++n)
          acc2[m][n] = __builtin_amdgcn_mfma_f32_16x16x32_f16(a2[m], vpre[kk][n], acc2[m][n], 0, 0, 0);
    }
  }
  const int b_ = bh >> 4, h = bh & 15;
#pragma unroll
  for (int m = 0; m < 4; ++m) {
#pragma unroll
    for (int n = 0; n < 2; ++n) {
#pragma unroll
      for (int r = 0; r < 4; ++r) {
        int i = ib * TI + wr * 64 + m * 16 + lk * 4 + r;
        int d = wc * 32 + n * 16 + l15;
        An[((size_t)(b_ * S_ + i)) * E_ + h * D_ + d] = (_Float16)acc2[m][n][r];
      }
    }
  }
}

// ---------------- output GEMM: out[m,n] = sum_k An[m,k]*Wo[n,k], fp32 out -----
__global__ __launch_bounds__(256) void gemm_out(const _Float16* __restrict__ An,
                                               const _Float16* __restrict__ Bw,
                                               float* __restrict__ outp) {
  const int K = 1024, BM = 128, BK = 32;
  __shared__ __align__(16) _Float16 As[BM * BK];
  __shared__ __align__(16) _Float16 Bs[BM * BK];
  const int tid = threadIdx.x, wave = tid >> 6, lane = tid & 63;
  const int l15 = lane & 15, lk = lane >> 4;
  const int wr = wave >> 1, wc = wave & 1;
  const int mb = blockIdx.x, nb = blockIdx.y;
  const int srow = (lane >> 2), scol = (lane & 3) * 8;
  f32x4 acc[4][4] = {};
  for (int kt = 0; kt < K / BK; ++kt) {
#pragma unroll
    for (int c = 0; c < 2; ++c) {
      int ch = wave * 2 + c;
      int row = ch * 16 + srow;
      gl_lds16(&An[(size_t)(mb * BM + row) * K + kt * BK + scol], &As[ch * 512]);
      gl_lds16(&Bw[(size_t)(nb * BM + row) * K + kt * BK + scol], &Bs[ch * 512]);
    }
    __syncthreads();
    f16x8 a[4], b[4];
#pragma unroll
    for (int m = 0; m < 4; ++m)
      a[m] = *reinterpret_cast<const f16x8*>(&As[(wr * 64 + m * 16 + l15) * BK + lk * 8]);
#pragma unroll
    for (int n = 0; n < 4; ++n)
      b[n] = *reinterpret_cast<const f16x8*>(&Bs[(wc * 64 + n * 16 + l15) * BK + lk * 8]);
#pragma unroll
    for (int m = 0; m < 4; ++m)
#pragma unroll
      for (int n = 0; n < 4; ++n)
        acc[m][n] = __builtin_amdgcn_mfma_f32_16x16x32_f16(a[m], b[n], acc[m][n], 0, 0, 0);
    __syncthreads();
  }
#pragma unroll
  for (int m = 0; m < 4; ++m) {
#pragma unroll
    for (int n = 0; n < 4; ++n) {
#pragma unroll
      for (int r = 0; r < 4; ++r) {
        int gm = mb * BM + wr * 64 + m * 16 + lk * 4 + r;
        int gn = nb * BM + wc * 64 + n * 16 + l15;
        outp[(size_t)gm * 1024 + gn] = acc[m][n][r];
      }
    }
  }
}

extern "C" void kernel_launch(void* const* d_in, const int* in_sizes, int n_in,
                              void* d_out, int out_size, void* d_ws, size_t ws_size,
                              hipStream_t stream) {
  const float* q = (const float*)d_in[0];
  const float* k = (const float*)d_in[1];
  const float* v = (const float*)d_in[2];
  const int* am = (const int*)d_in[3];
  const int* kpm = (const int*)d_in[4];
  const float* Wq = (const float*)d_in[5];
  const float* Wk = (const float*)d_in[6];
  const float* Wv = (const float*)d_in[7];
  const float* Wo = (const float*)d_in[8];
  float* out = (float*)d_out;

  _Float16* cvt = (_Float16*)d_ws;        // 16M f16 = 32 MiB
  _Float16* qkv = cvt;                    // q,k,v @ 0,4M,8M elems
  _Float16* wts = cvt + (12u << 20);      // Wq,Wk,Wv @ 12,13,14M elems
  _Float16* wob = cvt + (15u << 20);      // Wo @ 15M elems
  uint8_t* ws = (uint8_t*)d_ws;
  _Float16* Qh = (_Float16*)(ws + (32ull << 20));  // [BH,S,D] 8 MiB (pre-scaled /8)
  _Float16* Kh = (_Float16*)(ws + (40ull << 20));  // [BH,S,D] 8 MiB
  _Float16* Vt = (_Float16*)(ws + (48ull << 20));  // [BH,D,S] 8 MiB (then /denom)
  uint32_t* MW = (uint32_t*)(ws + (56ull << 20));  // packed mask 8 MiB
  _Float16* An = qkv;                              // reuse q region (dead after proj)

  cvt_f16<<<16384, 256, 0, stream>>>(q, k, v, Wq, Wk, Wv, Wo, cvt);
  pack_mask<<<65536, 256, 0, stream>>>(am, kpm, MW);
  gemm_proj<<<dim3(32, 8, 3), 256, 0, stream>>>(qkv, wts, Qh, Vt);
  attn_denom<<<dim3(8, 64), 256, 0, stream>>>(Qh, Kh, MW, Vt);
  attn_pv<<<dim3(8, 64), 256, 0, stream>>>(Qh, Kh, Vt, MW, An);
  gemm_out<<<dim3(32, 8), 256, 0, stream>>>(An, wob, out);
}

// Round 9
// 554.886 us; speedup vs baseline: 1.4805x; 1.0132x over previous
//
#include <hip/hip_runtime.h>
#include <stdint.h>

#define S_ 1024
#define E_ 1024
#define H_ 16
#define D_ 64
#define BH_ 64

typedef __attribute__((ext_vector_type(4))) float f32x4;
typedef __attribute__((ext_vector_type(8))) _Float16 f16x8;

__device__ __forceinline__ void gl_lds16(const void* g, void* l) {
  __builtin_amdgcn_global_load_lds((__attribute__((address_space(1))) void*)(g),
                                   (__attribute__((address_space(3))) void*)(l), 16, 0, 0);
}

// ------- merged: blocks [0,16384) fp32->fp16 convert; rest mask bit-pack ------
__global__ __launch_bounds__(256) void cvt_pack(const float* __restrict__ q,
                                                const float* __restrict__ k,
                                                const float* __restrict__ v,
                                                const float* __restrict__ wq,
                                                const float* __restrict__ wk,
                                                const float* __restrict__ wv,
                                                const float* __restrict__ wo,
                                                _Float16* __restrict__ dst,
                                                const int* __restrict__ am,
                                                const int* __restrict__ kpm,
                                                uint32_t* __restrict__ mw) {
  if (blockIdx.x < 16384) {
    size_t i = ((size_t)blockIdx.x * 256 + threadIdx.x) * 4;
    const size_t M4 = 4u << 20, M1 = 1u << 20;
    const float* src;
    size_t off;
    if (i < M4) { src = q; off = i; }
    else if (i < 2 * M4) { src = k; off = i - M4; }
    else if (i < 3 * M4) { src = v; off = i - 2 * M4; }
    else if (i < 3 * M4 + M1) { src = wq; off = i - 3 * M4; }
    else if (i < 3 * M4 + 2 * M1) { src = wk; off = i - (3 * M4 + M1); }
    else if (i < 3 * M4 + 3 * M1) { src = wv; off = i - (3 * M4 + 2 * M1); }
    else { src = wo; off = i - (3 * M4 + 3 * M1); }
    float4 f = *reinterpret_cast<const float4*>(src + off);
    _Float16 h[4];
    h[0] = (_Float16)f.x; h[1] = (_Float16)f.y; h[2] = (_Float16)f.z; h[3] = (_Float16)f.w;
    *reinterpret_cast<uint2*>(dst + i) = *reinterpret_cast<uint2*>(h);
  } else {
    size_t t = (size_t)(blockIdx.x - 16384) * 256 + threadIdx.x;  // elems [4t,4t+4)
    size_t f = t * 4;
    int k_ = (int)(f & (S_ - 1));
    int b = (int)(f >> 24);
    int4 a = *reinterpret_cast<const int4*>(am + f);
    int4 kp = *reinterpret_cast<const int4*>(kpm + (size_t)b * S_ + k_);
    uint32_t nib = (uint32_t)((a.x | kp.x) != 0) | ((uint32_t)((a.y | kp.y) != 0) << 1) |
                   ((uint32_t)((a.z | kp.z) != 0) << 2) | ((uint32_t)((a.w | kp.w) != 0) << 3);
    uint32_t v_ = nib << ((threadIdx.x & 7) * 4);
    v_ |= __shfl_xor(v_, 1);
    v_ |= __shfl_xor(v_, 2);
    v_ |= __shfl_xor(v_, 4);
    if ((threadIdx.x & 7) == 0) mw[t >> 3] = v_;
  }
}

// ---------------- fused projection GEMM: z=0 Q(/8), z=1 K, z=2 V(transposed) --
__global__ __launch_bounds__(256) void gemm_proj(const _Float16* __restrict__ qkv,
                                                 const _Float16* __restrict__ wts,
                                                 _Float16* __restrict__ QKo,
                                                 _Float16* __restrict__ Vt) {
  const int K = 1024, BM = 128, BK = 32;
  __shared__ __align__(16) _Float16 As[BM * BK];
  __shared__ __align__(16) _Float16 Bs[BM * BK];
  __shared__ __align__(16) _Float16 Ts[64 * 136];  // V-transpose staging
  const int tid = threadIdx.x, wave = tid >> 6, lane = tid & 63;
  const int l15 = lane & 15, lk = lane >> 4;
  const int wr = wave >> 1, wc = wave & 1;
  const int mb = blockIdx.x, nb = blockIdx.y, z = blockIdx.z;
  const _Float16* A = qkv + (size_t)z * (4u << 20);
  const _Float16* Bw = wts + (size_t)z * (1u << 20);
  const int srow = (lane >> 2);
  const int scol = (lane & 3) * 8;
  f32x4 acc[4][4] = {};
  for (int kt = 0; kt < K / BK; ++kt) {
#pragma unroll
    for (int c = 0; c < 2; ++c) {
      int ch = wave * 2 + c;
      int row = ch * 16 + srow;
      gl_lds16(&A[(size_t)(mb * BM + row) * K + kt * BK + scol], &As[ch * 512]);
      gl_lds16(&Bw[(size_t)(nb * BM + row) * K + kt * BK + scol], &Bs[ch * 512]);
    }
    __syncthreads();
    f16x8 a[4], b[4];
#pragma unroll
    for (int m = 0; m < 4; ++m)
      a[m] = *reinterpret_cast<const f16x8*>(&As[(wr * 64 + m * 16 + l15) * BK + lk * 8]);
#pragma unroll
    for (int n = 0; n < 4; ++n)
      b[n] = *reinterpret_cast<const f16x8*>(&Bs[(wc * 64 + n * 16 + l15) * BK + lk * 8]);
#pragma unroll
    for (int m = 0; m < 4; ++m)
#pragma unroll
      for (int n = 0; n < 4; ++n)
        acc[m][n] = __builtin_amdgcn_mfma_f32_16x16x32_f16(a[m], b[n], acc[m][n], 0, 0, 0);
    __syncthreads();
  }
  if (z == 2) {
    // coalesced Vt write via LDS transpose, one 64-d head-half at a time
    const int bb = mb >> 3, s0 = (mb & 7) * 128;
    for (int hh = 0; hh < 2; ++hh) {
      __syncthreads();
      if (wc == hh) {
#pragma unroll
        for (int m = 0; m < 4; ++m)
#pragma unroll
          for (int n = 0; n < 4; ++n)
#pragma unroll
            for (int r = 0; r < 4; ++r)
              Ts[(n * 16 + l15) * 136 + wr * 64 + m * 16 + lk * 4 + r] =
                  (_Float16)acc[m][n][r];
      }
      __syncthreads();
      int bh = bb * 16 + nb * 2 + hh;
#pragma unroll
      for (int u = 0; u < 4; ++u) {
        int c = tid + u * 256;
        int d = c >> 4, seg = c & 15;  // 64 rows x 16 uint4 segs = full 128 cols
        *reinterpret_cast<uint4*>(&Vt[(((size_t)bh * 64 + d) << 10) + s0 + seg * 8]) =
            *reinterpret_cast<const uint4*>(&Ts[d * 136 + seg * 8]);
      }
    }
  } else {
    const float qs = (z == 0) ? 0.125f : 1.0f;
#pragma unroll
    for (int m = 0; m < 4; ++m) {
#pragma unroll
      for (int n = 0; n < 4; ++n) {
#pragma unroll
        for (int r = 0; r < 4; ++r) {
          int gm = mb * BM + wr * 64 + m * 16 + lk * 4 + r;
          int gn = nb * BM + wc * 64 + n * 16 + l15;
          int bb = gm >> 10, s = gm & 1023, h = gn >> 6, d = gn & 63;
          int bh = bb * 16 + h;
          QKo[(size_t)z * (4u << 20) + ((size_t)bh * S_ + s) * D_ + d] =
              (_Float16)(acc[m][n][r] * qs);
        }
      }
    }
  }
}

// ---- attn_denom: denom[k] = sum_i (mask?1:exp(QK/8)); fold 1/denom into V ----
__global__ __launch_bounds__(256) void attn_denom(const _Float16* __restrict__ Qh,
                                                  const _Float16* __restrict__ Kh,
                                                  const uint32_t* __restrict__ mw,
                                                  _Float16* __restrict__ Vt) {
  const int TI = 128, TK = 128, LD = 72;
  __shared__ __align__(16) _Float16 Qs[TI * LD];
  __shared__ __align__(16) _Float16 Ks[TK * LD];
  __shared__ uint32_t Ms[TI * 4];
  __shared__ float red[4][64];
  __shared__ float dv[128];
  const int tid = threadIdx.x, wave = tid >> 6, lane = tid & 63;
  const int l15 = lane & 15, lk = lane >> 4;
  const int wr = wave >> 1, wc = wave & 1;
  const int bh = blockIdx.y, kb = blockIdx.x;
  const _Float16* Qb = Qh + (size_t)bh * S_ * D_;
  const _Float16* Kb = Kh + (size_t)bh * S_ * D_;
  const uint32_t* mrow = mw + (size_t)bh * S_ * 32;
#pragma unroll
  for (int j = 0; j < 4; ++j) {
    int c = tid + j * 256;
    int row = c >> 3, c8 = c & 7;
    *reinterpret_cast<uint4*>(&Ks[row * LD + c8 * 8]) =
        *reinterpret_cast<const uint4*>(&Kb[(size_t)(kb * TK + row) * D_ + c8 * 8]);
  }
  float csum[4] = {0.f, 0.f, 0.f, 0.f};
  for (int ib = 0; ib < S_ / TI; ++ib) {
    __syncthreads();
#pragma unroll
    for (int j = 0; j < 4; ++j) {
      int c = tid + j * 256;
      int row = c >> 3, c8 = c & 7;
      *reinterpret_cast<uint4*>(&Qs[row * LD + c8 * 8]) =
          *reinterpret_cast<const uint4*>(&Qb[(size_t)(ib * TI + row) * D_ + c8 * 8]);
    }
    Ms[tid] = mrow[(size_t)(ib * TI + (tid >> 2)) * 32 + kb * 4 + (tid & 3)];
    Ms[tid + 256] = mrow[(size_t)(ib * TI + 64 + (tid >> 2)) * 32 + kb * 4 + (tid & 3)];
    __syncthreads();
    f32x4 acc[4][4] = {};
#pragma unroll
    for (int kk = 0; kk < 2; ++kk) {
      f16x8 a[4], b[4];
#pragma unroll
      for (int m = 0; m < 4; ++m)
        a[m] = *reinterpret_cast<const f16x8*>(&Qs[(wr * 64 + m * 16 + l15) * LD + kk * 32 + lk * 8]);
#pragma unroll
      for (int n = 0; n < 4; ++n)
        b[n] = *reinterpret_cast<const f16x8*>(&Ks[(wc * 64 + n * 16 + l15) * LD + kk * 32 + lk * 8]);
#pragma unroll
      for (int m = 0; m < 4; ++m)
#pragma unroll
        for (int n = 0; n < 4; ++n)
          acc[m][n] = __builtin_amdgcn_mfma_f32_16x16x32_f16(a[m], b[n], acc[m][n], 0, 0, 0);
    }
#pragma unroll
    for (int n = 0; n < 4; ++n) {
      int kcol = wc * 64 + n * 16 + l15;
      int kwl = kcol >> 5;
      int kbit = kcol & 31;
      float part = 0.f;
#pragma unroll
      for (int m = 0; m < 4; ++m) {
        int lr0 = wr * 64 + m * 16 + lk * 4;
#pragma unroll
        for (int r = 0; r < 4; ++r) {
          bool msk = (Ms[(lr0 + r) * 4 + kwl] >> kbit) & 1;
          float e = __expf(acc[m][n][r]);  // Q pre-scaled by 1/8
          part += msk ? 1.0f : e;
        }
      }
      csum[n] += part;
    }
  }
#pragma unroll
  for (int n = 0; n < 4; ++n) {
    float v = csum[n];
    v += __shfl_xor(v, 16);
    v += __shfl_xor(v, 32);
    csum[n] = v;
  }
  __syncthreads();
  if (lane < 16) {
#pragma unroll
    for (int n = 0; n < 4; ++n) red[wave][n * 16 + l15] = csum[n];
  }
  __syncthreads();
  if (tid < 128) dv[tid] = 1.0f / (red[tid >> 6][tid & 63] + red[(tid >> 6) + 2][tid & 63]);
  __syncthreads();
  // scale V[bh][d][kb*128 .. +128] by 1/denom[k] (coalesced 16B per lane)
  _Float16* Vblk = Vt + ((size_t)bh << 16) + kb * TK;
#pragma unroll
  for (int u = 0; u < 4; ++u) {
    int c = tid + u * 256;
    int d = c >> 4, k8 = (c & 15) * 8;
    _Float16* p = Vblk + (size_t)d * 1024 + k8;
    uint4 raw = *reinterpret_cast<uint4*>(p);
    _Float16* h = reinterpret_cast<_Float16*>(&raw);
#pragma unroll
    for (int j = 0; j < 8; ++j) h[j] = (_Float16)((float)h[j] * dv[k8 + j]);
    *reinterpret_cast<uint4*>(p) = raw;
  }
}

// ---- attn_pv: An[i,d] = sum_k (mask?0:exp(QK/8)) * V'[d,k] (fused, no Wg) ----
__global__ __launch_bounds__(256) void attn_pv(const _Float16* __restrict__ Qh,
                                               const _Float16* __restrict__ Kh,
                                               const _Float16* __restrict__ Vp,
                                               const uint32_t* __restrict__ mw,
                                               _Float16* __restrict__ An) {
  const int TI = 128, TK = 128, LD = 72, LW = 136;
  __shared__ __align__(16) _Float16 Qs[TI * LD];   // 18 KB
  __shared__ __align__(16) _Float16 Ks[TK * LD];   // 18 KB
  __shared__ __align__(16) _Float16 Ws[TI * LW];   // 34 KB
  __shared__ uint32_t Ms[TI * 4];                  // 2 KB
  const int tid = threadIdx.x, wave = tid >> 6, lane = tid & 63;
  const int l15 = lane & 15, lk = lane >> 4;
  const int wr = wave >> 1, wc = wave & 1;
  const int bh = blockIdx.y, ib = blockIdx.x;
  const _Float16* Qb = Qh + (size_t)bh * S_ * D_;
  const _Float16* Kb = Kh + (size_t)bh * S_ * D_;
  const _Float16* Vb = Vp + ((size_t)bh << 16);
  const uint32_t* mrow = mw + (size_t)bh * S_ * 32;
  // stage Q once
#pragma unroll
  for (int j = 0; j < 4; ++j) {
    int c = tid + j * 256;
    int row = c >> 3, c8 = c & 7;
    *reinterpret_cast<uint4*>(&Qs[row * LD + c8 * 8]) =
        *reinterpret_cast<const uint4*>(&Qb[(size_t)(ib * TI + row) * D_ + c8 * 8]);
  }
  f32x4 acc2[4][2] = {};
  for (int kt = 0; kt < S_ / TK; ++kt) {
    // prefetch V fragments for this k-tile into registers (hides under QK^T)
    f16x8 vpre[4][2];
#pragma unroll
    for (int kk = 0; kk < 4; ++kk)
#pragma unroll
      for (int n = 0; n < 2; ++n)
        vpre[kk][n] = *reinterpret_cast<const f16x8*>(
            &Vb[(size_t)(wc * 32 + n * 16 + l15) * S_ + kt * TK + kk * 32 + lk * 8]);
    __syncthreads();  // B1: prev PV done (Ws,Ks free)
#pragma unroll
    for (int j = 0; j < 4; ++j) {
      int c = tid + j * 256;
      int row = c >> 3, c8 = c & 7;
      *reinterpret_cast<uint4*>(&Ks[row * LD + c8 * 8]) =
          *reinterpret_cast<const uint4*>(&Kb[(size_t)(kt * TK + row) * D_ + c8 * 8]);
    }
    Ms[tid] = mrow[(size_t)(ib * TI + (tid >> 2)) * 32 + kt * 4 + (tid & 3)];
    Ms[tid + 256] = mrow[(size_t)(ib * TI + 64 + (tid >> 2)) * 32 + kt * 4 + (tid & 3)];
    __syncthreads();  // B2: Ks/Ms visible
    f32x4 acc[4][4] = {};
#pragma unroll
    for (int kk = 0; kk < 2; ++kk) {
      f16x8 a[4], b[4];
#pragma unroll
      for (int m = 0; m < 4; ++m)
        a[m] = *reinterpret_cast<const f16x8*>(&Qs[(wr * 64 + m * 16 + l15) * LD + kk * 32 + lk * 8]);
#pragma unroll
      for (int n = 0; n < 4; ++n)
        b[n] = *reinterpret_cast<const f16x8*>(&Ks[(wc * 64 + n * 16 + l15) * LD + kk * 32 + lk * 8]);
#pragma unroll
      for (int m = 0; m < 4; ++m)
#pragma unroll
        for (int n = 0; n < 4; ++n)
          acc[m][n] = __builtin_amdgcn_mfma_f32_16x16x32_f16(a[m], b[n], acc[m][n], 0, 0, 0);
    }
    // masked exp -> Ws (unnormalized; denom folded into V')
#pragma unroll
    for (int n = 0; n < 4; ++n) {
      int kcol = wc * 64 + n * 16 + l15;
      int kwl = kcol >> 5;
      int kbit = kcol & 31;
#pragma unroll
      for (int m = 0; m < 4; ++m) {
        int lr0 = wr * 64 + m * 16 + lk * 4;
#pragma unroll
        for (int r = 0; r < 4; ++r) {
          bool msk = (Ms[(lr0 + r) * 4 + kwl] >> kbit) & 1;
          float e = __expf(acc[m][n][r]);
          Ws[(lr0 + r) * LW + kcol] = msk ? (_Float16)0.f : (_Float16)e;
        }
      }
    }
    __syncthreads();  // B3: Ws complete
    // PV: acc2 += Ws(i,k) x V'(d,k); V' from registers
#pragma unroll
    for (int kk = 0; kk < 4; ++kk) {
      f16x8 a2[4];
#pragma unroll
      for (int m = 0; m < 4; ++m)
        a2[m] = *reinterpret_cast<const f16x8*>(&Ws[(wr * 64 + m * 16 + l15) * LW + kk * 32 + lk * 8]);
#pragma unroll
      for (int m = 0; m < 4; ++m)
#pragma unroll
        for (int n = 0; n < 2; ++n)
          acc2[m][n] = __builtin_amdgcn_mfma_f32_16x16x32_f16(a2[m], vpre[kk][n], acc2[m][n], 0, 0, 0);
    }
  }
  const int b_ = bh >> 4, h = bh & 15;
#pragma unroll
  for (int m = 0; m < 4; ++m) {
#pragma unroll
    for (int n = 0; n < 2; ++n) {
#pragma unroll
      for (int r = 0; r < 4; ++r) {
        int i = ib * TI + wr * 64 + m * 16 + lk * 4 + r;
        int d = wc * 32 + n * 16 + l15;
        An[((size_t)(b_ * S_ + i)) * E_ + h * D_ + d] = (_Float16)acc2[m][n][r];
      }
    }
  }
}

// ------- output GEMM: out[m,n] = sum_k An[m,k]*Wo[n,k]; 64x128 tile, fp32 out -
__global__ __launch_bounds__(256) void gemm_out(const _Float16* __restrict__ An,
                                               const _Float16* __restrict__ Bw,
                                               float* __restrict__ outp) {
  const int K = 1024, BM = 64, BN = 128, BK = 32;
  __shared__ __align__(16) _Float16 As[BM * BK];
  __shared__ __align__(16) _Float16 Bs[BN * BK];
  const int tid = threadIdx.x, wave = tid >> 6, lane = tid & 63;
  const int l15 = lane & 15, lk = lane >> 4;
  const int wr = wave >> 1, wc = wave & 1;
  const int mb = blockIdx.x, nb = blockIdx.y;
  f32x4 acc[2][4] = {};
  for (int kt = 0; kt < K / BK; ++kt) {
    {  // A: 64x32 = one 16B chunk per thread
      int row = tid >> 2, col8 = (tid & 3) * 8;
      gl_lds16(&An[(size_t)(mb * BM + row) * K + kt * BK + col8], &As[tid * 8]);
    }
#pragma unroll
    for (int j = 0; j < 2; ++j) {  // B: 128x32 = two chunks
      int c = tid + j * 256;
      int row = c >> 2, col8 = (c & 3) * 8;
      gl_lds16(&Bw[(size_t)(nb * BN + row) * K + kt * BK + col8], &Bs[c * 8]);
    }
    __syncthreads();
    f16x8 a[2], b[4];
#pragma unroll
    for (int m = 0; m < 2; ++m)
      a[m] = *reinterpret_cast<const f16x8*>(&As[(wr * 32 + m * 16 + l15) * BK + lk * 8]);
#pragma unroll
    for (int n = 0; n < 4; ++n)
      b[n] = *reinterpret_cast<const f16x8*>(&Bs[(wc * 64 + n * 16 + l15) * BK + lk * 8]);
#pragma unroll
    for (int m = 0; m < 2; ++m)
#pragma unroll
      for (int n = 0; n < 4; ++n)
        acc[m][n] = __builtin_amdgcn_mfma_f32_16x16x32_f16(a[m], b[n], acc[m][n], 0, 0, 0);
    __syncthreads();
  }
#pragma unroll
  for (int m = 0; m < 2; ++m) {
#pragma unroll
    for (int n = 0; n < 4; ++n) {
#pragma unroll
      for (int r = 0; r < 4; ++r) {
        int gm = mb * BM + wr * 32 + m * 16 + lk * 4 + r;
        int gn = nb * BN + wc * 64 + n * 16 + l15;
        outp[(size_t)gm * 1024 + gn] = acc[m][n][r];
      }
    }
  }
}

extern "C" void kernel_launch(void* const* d_in, const int* in_sizes, int n_in,
                              void* d_out, int out_size, void* d_ws, size_t ws_size,
                              hipStream_t stream) {
  const float* q = (const float*)d_in[0];
  const float* k = (const float*)d_in[1];
  const float* v = (const float*)d_in[2];
  const int* am = (const int*)d_in[3];
  const int* kpm = (const int*)d_in[4];
  const float* Wq = (const float*)d_in[5];
  const float* Wk = (const float*)d_in[6];
  const float* Wv = (const float*)d_in[7];
  const float* Wo = (const float*)d_in[8];
  float* out = (float*)d_out;

  _Float16* cvt = (_Float16*)d_ws;        // 16M f16 = 32 MiB
  _Float16* qkv = cvt;                    // q,k,v @ 0,4M,8M elems
  _Float16* wts = cvt + (12u << 20);      // Wq,Wk,Wv @ 12,13,14M elems
  _Float16* wob = cvt + (15u << 20);      // Wo @ 15M elems
  uint8_t* ws = (uint8_t*)d_ws;
  _Float16* Qh = (_Float16*)(ws + (32ull << 20));  // [BH,S,D] 8 MiB (pre-scaled /8)
  _Float16* Kh = (_Float16*)(ws + (40ull << 20));  // [BH,S,D] 8 MiB
  _Float16* Vt = (_Float16*)(ws + (48ull << 20));  // [BH,D,S] 8 MiB (then /denom)
  uint32_t* MW = (uint32_t*)(ws + (56ull << 20));  // packed mask 8 MiB
  _Float16* An = qkv;                              // reuse q region (dead after proj)

  cvt_pack<<<16384 + 65536, 256, 0, stream>>>(q, k, v, Wq, Wk, Wv, Wo, cvt, am, kpm, MW);
  gemm_proj<<<dim3(32, 8, 3), 256, 0, stream>>>(qkv, wts, Qh, Vt);
  attn_denom<<<dim3(8, 64), 256, 0, stream>>>(Qh, Kh, MW, Vt);
  attn_pv<<<dim3(8, 64), 256, 0, stream>>>(Qh, Kh, Vt, MW, An);
  gemm_out<<<dim3(64, 8), 256, 0, stream>>>(An, wob, out);
}